// Round 3
// baseline (1548.567 us; speedup 1.0000x reference)
//
#include <hip/hip_runtime.h>
#include <cstdint>
#include <cstddef>

#define NB 4
#define NS 4096
#define ND 2048
#define NH 16
#define NHD 128
#define NT 1024
#define NF 8192

typedef __bf16 bf16;
typedef __bf16 bf16x8 __attribute__((ext_vector_type(8)));
typedef __bf16 bf16x4 __attribute__((ext_vector_type(4)));
typedef float  f32x4  __attribute__((ext_vector_type(4)));

typedef const __attribute__((address_space(1))) void* gptr_t;
typedef __attribute__((address_space(3))) void* lptr_t;

__device__ __forceinline__ float wave_sum(float v) {
#pragma unroll
    for (int off = 32; off > 0; off >>= 1) v += __shfl_xor(v, off);
    return v;
}
__device__ __forceinline__ float wave_max(float v) {
#pragma unroll
    for (int off = 32; off > 0; off >>= 1) v = fmaxf(v, __shfl_xor(v, off));
    return v;
}

// ---------------------------------------------------------------------------
// Router: logits[row] = dot(x[row,:], w_router)   (row = b*NS+s)
// ---------------------------------------------------------------------------
__global__ __launch_bounds__(256) void router_k(const float* __restrict__ x,
                                                const float* __restrict__ wr,
                                                float* __restrict__ logits) {
    __shared__ float r4[4];
    long long row = blockIdx.x;
    const float4* xr = (const float4*)(x + row * ND);
    const float4* w4 = (const float4*)wr;
    float p = 0.f;
    for (int i = threadIdx.x; i < ND / 4; i += 256) {
        float4 a = xr[i], b = w4[i];
        p += a.x * b.x + a.y * b.y + a.z * b.z + a.w * b.w;
    }
    p = wave_sum(p);
    if ((threadIdx.x & 63) == 0) r4[threadIdx.x >> 6] = p;
    __syncthreads();
    if (threadIdx.x == 0) logits[row] = r4[0] + r4[1] + r4[2] + r4[3];
}

// ---------------------------------------------------------------------------
// Top-K (exact, matches jax.lax.top_k tie-break) + index sort + router softmax.
// ---------------------------------------------------------------------------
__global__ __launch_bounds__(1024) void topk_k(const float* __restrict__ logits,
                                               int* __restrict__ sel,
                                               float* __restrict__ rw) {
    __shared__ unsigned long long keys[NS];   // 32 KB
    __shared__ float r16[16];
    __shared__ float bmax, bsum;
    const int bb = blockIdx.x;
    const int tid = threadIdx.x;
    const float* lg = logits + (long long)bb * NS;

    for (int i = tid; i < NS; i += 1024) {
        unsigned u = __float_as_uint(lg[i]);
        u = (u & 0x80000000u) ? ~u : (u | 0x80000000u);   // order-preserving map
        keys[i] = ((unsigned long long)u << 32) | (unsigned)(NS - 1 - i);
    }
    __syncthreads();
    for (int k = 2; k <= NS; k <<= 1) {
        for (int j = k >> 1; j > 0; j >>= 1) {
            for (int i = tid; i < NS; i += 1024) {
                int ixj = i ^ j;
                if (ixj > i) {
                    unsigned long long a = keys[i], c = keys[ixj];
                    bool up = ((i & k) == 0);
                    if (up ? (a < c) : (a > c)) { keys[i] = c; keys[ixj] = a; }
                }
            }
            __syncthreads();
        }
    }
    unsigned long long a0 = keys[tid];
    __syncthreads();
    {
        unsigned idx_ = NS - 1 - (unsigned)(a0 & 0xFFFFFFFFu);
        unsigned uval = (unsigned)(a0 >> 32);
        keys[tid] = ((unsigned long long)idx_ << 32) | uval;
    }
    __syncthreads();
    for (int k = 2; k <= NT; k <<= 1) {
        for (int j = k >> 1; j > 0; j >>= 1) {
            int i = tid, ixj = i ^ j;
            if (i < NT && ixj > i) {
                unsigned long long a = keys[i], c = keys[ixj];
                bool up = ((i & k) == 0);
                if (up ? (a > c) : (a < c)) { keys[i] = c; keys[ixj] = a; }
            }
            __syncthreads();
        }
    }
    unsigned long long kk = keys[tid];
    int si = (int)(kk >> 32);
    unsigned u = (unsigned)(kk & 0xFFFFFFFFu);
    u = (u & 0x80000000u) ? (u ^ 0x80000000u) : ~u;
    float val = __uint_as_float(u);

    const int wid = tid >> 6, lane = tid & 63;
    float mx = wave_max(val);
    if (lane == 0) r16[wid] = mx;
    __syncthreads();
    if (tid == 0) {
        float m = r16[0];
        for (int i = 1; i < 16; i++) m = fmaxf(m, r16[i]);
        bmax = m;
    }
    __syncthreads();
    float e = __expf(val - bmax);
    float s = wave_sum(e);
    if (lane == 0) r16[wid] = s;
    __syncthreads();
    if (tid == 0) {
        float t = 0.f;
        for (int i = 0; i < 16; i++) t += r16[i];
        bsum = t;
    }
    __syncthreads();
    sel[bb * NT + tid] = si;
    rw[bb * NT + tid] = e / bsum;
}

// ---------------------------------------------------------------------------
// Gather: xf[b,j,:] = x[b, sel[b,j], :]   (float4)
// ---------------------------------------------------------------------------
__global__ __launch_bounds__(256) void gather_k(const float* __restrict__ x,
                                                const int* __restrict__ sel,
                                                float* __restrict__ xf) {
    int gid = blockIdx.x * 256 + threadIdx.x;
    int col = gid & (ND / 4 - 1);
    int row = gid >> 9;
    int bb = row >> 10;
    int s = sel[row];
    ((float4*)xf)[gid] = ((const float4*)x)[((long long)bb * NS + s) * (ND / 4) + col];
}

// ---------------------------------------------------------------------------
// RMSNorm row kernel: out = bf16(x * rsqrt(mean(x^2)+eps) * g)
// ---------------------------------------------------------------------------
__global__ __launch_bounds__(256) void rmsnorm_k(const float* __restrict__ x,
                                                 const float* __restrict__ g,
                                                 bf16* __restrict__ out) {
    __shared__ float r4[4];
    __shared__ float scl;
    long long row = blockIdx.x;
    const float4* xr = (const float4*)(x + row * ND);
    int i0 = threadIdx.x, i1 = threadIdx.x + 256;
    float4 a = xr[i0], b = xr[i1];
    float ss = a.x * a.x + a.y * a.y + a.z * a.z + a.w * a.w +
               b.x * b.x + b.y * b.y + b.z * b.z + b.w * b.w;
    ss = wave_sum(ss);
    if ((threadIdx.x & 63) == 0) r4[threadIdx.x >> 6] = ss;
    __syncthreads();
    if (threadIdx.x == 0)
        scl = rsqrtf((r4[0] + r4[1] + r4[2] + r4[3]) * (1.0f / ND) + 1e-6f);
    __syncthreads();
    float s = scl;
    const float4* g4 = (const float4*)g;
    float4 ga = g4[i0], gb = g4[i1];
    bf16x4 o0, o1;
    o0[0] = (bf16)(a.x * s * ga.x); o0[1] = (bf16)(a.y * s * ga.y);
    o0[2] = (bf16)(a.z * s * ga.z); o0[3] = (bf16)(a.w * s * ga.w);
    o1[0] = (bf16)(b.x * s * gb.x); o1[1] = (bf16)(b.y * s * gb.y);
    o1[2] = (bf16)(b.z * s * gb.z); o1[3] = (bf16)(b.w * s * gb.w);
    *(bf16x4*)(out + row * ND + i0 * 4) = o0;
    *(bf16x4*)(out + row * ND + i1 * 4) = o1;
}

// ---------------------------------------------------------------------------
// Transpose + fp32->bf16: out[c][r] = in[r][c]; in is R x C. dims %32 == 0.
// ---------------------------------------------------------------------------
__global__ __launch_bounds__(256) void transpose_to_bf16(const float* __restrict__ in,
                                                         bf16* __restrict__ out,
                                                         int R, int C) {
    __shared__ float tile[32][33];
    int bx = blockIdx.x * 32;   // col
    int by = blockIdx.y * 32;   // row
    int tx = threadIdx.x & 31;
    int ty = threadIdx.x >> 5;   // 0..7
#pragma unroll
    for (int i = 0; i < 4; i++)
        tile[ty + 8 * i][tx] = in[(long long)(by + ty + 8 * i) * C + bx + tx];
    __syncthreads();
#pragma unroll
    for (int i = 0; i < 4; i++)
        out[(long long)(bx + ty + 8 * i) * R + by + tx] = (bf16)tile[tx][ty + 8 * i];
}

// ---------------------------------------------------------------------------
// RoPE + layout shuffle (reads fused QKV buffer, row stride 3*ND)
// ---------------------------------------------------------------------------
__global__ __launch_bounds__(256) void rope_k(const bf16* __restrict__ QKV,
                                              const float* __restrict__ fr,
                                              bf16* __restrict__ Q,
                                              bf16* __restrict__ K,
                                              bf16* __restrict__ Vt) {
    int gid = blockIdx.x * 256 + threadIdx.x;
    int hd = gid & 63;
    int h = (gid >> 6) & 15;
    int t = (gid >> 10) & (NT - 1);
    int bb = gid >> 20;
    float c = fr[t * 128 + hd * 2 + 0];
    float s = fr[t * 128 + hd * 2 + 1];
    long long base = ((long long)bb * NT + t) * (3 * ND) + h * NHD;
    float q1 = (float)QKV[base + hd],      q2 = (float)QKV[base + hd + 64];
    float k1 = (float)QKV[base + ND + hd], k2 = (float)QKV[base + ND + hd + 64];
    long long ob = (((long long)(bb * NH + h)) * NT + t) * NHD;
    Q[ob + hd]      = (bf16)(q1 * c - q2 * s);
    Q[ob + hd + 64] = (bf16)(q1 * s + q2 * c);
    K[ob + hd]      = (bf16)(k1 * c - k2 * s);
    K[ob + hd + 64] = (bf16)(k1 * s + k2 * c);
    long long vb = ((long long)(bb * NH + h)) * NHD * NT + t;
    Vt[vb + (long long)hd * NT]        = QKV[base + 2 * ND + hd];
    Vt[vb + (long long)(hd + 64) * NT] = QKV[base + 2 * ND + hd + 64];
}

// ---------------------------------------------------------------------------
// Row softmax (T=1024 cols): P = bf16(softmax(scores_row))
// ---------------------------------------------------------------------------
__global__ __launch_bounds__(256) void softmax_k(const float* __restrict__ Sc,
                                                 bf16* __restrict__ P) {
    __shared__ float r4[4];
    __shared__ float bc;
    long long row = blockIdx.x;
    float4 v = ((const float4*)(Sc + row * NT))[threadIdx.x];
    float mx = fmaxf(fmaxf(v.x, v.y), fmaxf(v.z, v.w));
    mx = wave_max(mx);
    if ((threadIdx.x & 63) == 0) r4[threadIdx.x >> 6] = mx;
    __syncthreads();
    if (threadIdx.x == 0) bc = fmaxf(fmaxf(r4[0], r4[1]), fmaxf(r4[2], r4[3]));
    __syncthreads();
    float m = bc;
    float e0 = __expf(v.x - m), e1 = __expf(v.y - m);
    float e2 = __expf(v.z - m), e3 = __expf(v.w - m);
    float ss = wave_sum(e0 + e1 + e2 + e3);
    if ((threadIdx.x & 63) == 0) r4[threadIdx.x >> 6] = ss;
    __syncthreads();
    if (threadIdx.x == 0) bc = 1.f / (r4[0] + r4[1] + r4[2] + r4[3]);
    __syncthreads();
    float inv = bc;
    bf16x4 o;
    o[0] = (bf16)(e0 * inv); o[1] = (bf16)(e1 * inv);
    o[2] = (bf16)(e2 * inv); o[3] = (bf16)(e3 * inv);
    *(bf16x4*)(P + row * NT + threadIdx.x * 4) = o;
}

// ---------------------------------------------------------------------------
__global__ __launch_bounds__(256) void copy_k(const float4* __restrict__ in,
                                              float4* __restrict__ out, long long n) {
    for (long long i = (long long)blockIdx.x * 256 + threadIdx.x; i < n;
         i += (long long)gridDim.x * 256)
        out[i] = in[i];
}

// ---------------------------------------------------------------------------
// MFMA GEMM (m97 structure) — kept for attention shapes (K=128 / N=128).
// MODE 0: C bf16 = alpha*acc     MODE 1: C fp32 = alpha*acc
// ---------------------------------------------------------------------------
template <int MODE>
__global__ __launch_bounds__(256, 2) void gemm_bt(
    const bf16* __restrict__ A, int lda, long long sAz,
    const bf16* __restrict__ Bt, int ldb, long long sBz,
    void* __restrict__ Cv, long long sCz, int ldc,
    int K, float alpha,
    const float* __restrict__ res, const int* __restrict__ selp,
    const float* __restrict__ rwp, float* __restrict__ outp) {
    __shared__ bf16 As[128][32];   // 8 KB, unpadded (global_load_lds layout)
    __shared__ bf16 Bs[128][32];

    const int tid = threadIdx.x;
    const int lane = tid & 63;
    const int wave = tid >> 6;
    const int wm = wave >> 1, wn = wave & 1;
    const int lm = lane & 15, lq = lane >> 4;

    const int m0 = blockIdx.y * 128;
    const int n0 = blockIdx.x * 128;
    const int z = blockIdx.z;

    A += (long long)z * sAz;
    Bt += (long long)z * sBz;

    f32x4 acc[4][4];
#pragma unroll
    for (int i = 0; i < 4; i++)
#pragma unroll
        for (int j = 0; j < 4; j++) {
            f32x4 zz = {0.f, 0.f, 0.f, 0.f};
            acc[i][j] = zz;
        }

    const int sr = wave * 16 + (lane >> 2);
    const int sk = (lane & 3) * 8;
    const bf16* gA0 = A + (long long)(m0 + sr) * lda + sk;
    const bf16* gA1 = gA0 + (long long)64 * lda;
    const bf16* gB0 = Bt + (long long)(n0 + sr) * ldb + sk;
    const bf16* gB1 = gB0 + (long long)64 * ldb;
    bf16* lA0 = &As[sr][sk];
    bf16* lA1 = &As[sr + 64][sk];
    bf16* lB0 = &Bs[sr][sk];
    bf16* lB1 = &Bs[sr + 64][sk];

    for (int k0 = 0; k0 < K; k0 += 32) {
        __builtin_amdgcn_global_load_lds((gptr_t)(gA0 + k0), (lptr_t)lA0, 16, 0, 0);
        __builtin_amdgcn_global_load_lds((gptr_t)(gA1 + k0), (lptr_t)lA1, 16, 0, 0);
        __builtin_amdgcn_global_load_lds((gptr_t)(gB0 + k0), (lptr_t)lB0, 16, 0, 0);
        __builtin_amdgcn_global_load_lds((gptr_t)(gB1 + k0), (lptr_t)lB1, 16, 0, 0);
        __syncthreads();

        bf16x8 af[4], bfr[4];
#pragma unroll
        for (int mi = 0; mi < 4; mi++)
            af[mi] = *(const bf16x8*)&As[wm * 64 + mi * 16 + lm][lq * 8];
#pragma unroll
        for (int ni = 0; ni < 4; ni++)
            bfr[ni] = *(const bf16x8*)&Bs[wn * 64 + ni * 16 + lm][lq * 8];
#pragma unroll
        for (int mi = 0; mi < 4; mi++)
#pragma unroll
            for (int ni = 0; ni < 4; ni++)
                acc[mi][ni] = __builtin_amdgcn_mfma_f32_16x16x32_bf16(
                    af[mi], bfr[ni], acc[mi][ni], 0, 0, 0);
        __syncthreads();
    }

#pragma unroll
    for (int mi = 0; mi < 4; mi++) {
#pragma unroll
        for (int ni = 0; ni < 4; ni++) {
            int row = m0 + wm * 64 + mi * 16 + lq * 4;
            int col = n0 + wn * 64 + ni * 16 + lm;
#pragma unroll
            for (int r = 0; r < 4; r++) {
                float v = alpha * acc[mi][ni][r];
                long long rr = row + r;
                if constexpr (MODE == 0) {
                    bf16* C = (bf16*)Cv + (long long)z * sCz;
                    C[rr * ldc + col] = (bf16)v;
                } else {
                    float* C = (float*)Cv + (long long)z * sCz;
                    C[rr * ldc + col] = v;
                }
            }
        }
    }
}

// ---------------------------------------------------------------------------
// 256x256 8-phase pipelined GEMM (m201-template port: T2+T3+T4+T5).
//   C(MxN) = A(MxK).Bt(NxK)^T, bf16 in, fp32 accum. BK=64, 8 waves (2Mx4N),
//   per-wave 128x64 out, 16x16x32 MFMA, LDS 128 KiB double-buffered.
//   2 K-tiles/iteration, 8 phases; per phase: {ds-read quadrant frags |
//   stage 1 half-tile (2 gload_lds)} -> barrier -> lgkmcnt(0) ->
//   setprio(1) 16 MFMA setprio(0) -> barrier. vmcnt(4) at phases 4/8 only.
//   Staging ledger (steady state, loads/thread): enter P1 with 4 in flight
//   (A(t1)); P1,P2 stage B(t1); P3,P4 stage A(t2); vmcnt(4) at P4 leaves
//   A(t2) flying; P5,P6 stage B(t2); P7,P8 stage A(t3); vmcnt(4) at P8.
//   Last iteration: no t2/t3 staging, vmcnt(0) at P4 (B(t1) is newest).
//   LDS linear dest + XOR-swizzled global source; ds_read same XOR (T2).
// MODE 0: C bf16 = alpha*acc            MODE 2: C fp32 atomic += acc
// MODE 3: C bf16 = silu(acc)            MODE 4: C bf16 *= acc
// MODE 5: out[(b*NS+sel[m])*ND+n] atomic += rw[m]*(acc + (z==0)*res)
// ---------------------------------------------------------------------------
#define G256_BAR() do { __builtin_amdgcn_sched_barrier(0); \
    __builtin_amdgcn_s_barrier(); __builtin_amdgcn_sched_barrier(0); } while (0)
#define G256_LGKM0() do { asm volatile("s_waitcnt lgkmcnt(0)" ::: "memory"); \
    __builtin_amdgcn_sched_barrier(0); } while (0)
#define G256_VMC(n) do { asm volatile("s_waitcnt vmcnt(" #n ")" ::: "memory"); \
    __builtin_amdgcn_sched_barrier(0); } while (0)

#define STAGE_A(c, h, t) do { \
    char* _l = sm + (c) * 65536 + (h) * 16384 + sdst; \
    long long _ko = (long long)(t) * 64; \
    __builtin_amdgcn_global_load_lds((gptr_t)(gA + (2 * (h)) * stA + _ko), \
                                     (lptr_t)_l, 16, 0, 0); \
    __builtin_amdgcn_global_load_lds((gptr_t)(gA + (2 * (h) + 1) * stA + _ko), \
                                     (lptr_t)(_l + 8192), 16, 0, 0); \
} while (0)
#define STAGE_B(c, h, t) do { \
    char* _l = sm + (c) * 65536 + 32768 + (h) * 16384 + sdst; \
    long long _ko = (long long)(t) * 64; \
    __builtin_amdgcn_global_load_lds((gptr_t)(gB + (2 * (h)) * stB + _ko), \
                                     (lptr_t)_l, 16, 0, 0); \
    __builtin_amdgcn_global_load_lds((gptr_t)(gB + (2 * (h) + 1) * stB + _ko), \
                                     (lptr_t)(_l + 8192), 16, 0, 0); \
} while (0)

#define LDA_HALF(c, lo) do { \
    char* _b = sm + (c) * 65536; \
    _Pragma("unroll") \
    for (int _mi = 0; _mi < 4; _mi++) { \
        a[(lo) + _mi][0] = *(const bf16x8*)(_b + aoff + ((lo) + _mi) * 2048); \
        a[(lo) + _mi][1] = *(const bf16x8*)(_b + (aoff ^ 64) + ((lo) + _mi) * 2048); \
    } \
} while (0)
#define LDB_HALF(c, lo) do { \
    char* _b = sm + (c) * 65536 + 32768; \
    _Pragma("unroll") \
    for (int _ni = 0; _ni < 2; _ni++) { \
        b[(lo) + _ni][0] = *(const bf16x8*)(_b + boff + ((lo) + _ni) * 2048); \
        b[(lo) + _ni][1] = *(const bf16x8*)(_b + (boff ^ 64) + ((lo) + _ni) * 2048); \
    } \
} while (0)

#define MFMA_Q(mlo, nlo) do { \
    __builtin_amdgcn_s_setprio(1); \
    _Pragma("unroll") \
    for (int _ks = 0; _ks < 2; _ks++) \
    _Pragma("unroll") \
    for (int _mi = 0; _mi < 4; _mi++) \
    _Pragma("unroll") \
    for (int _ni = 0; _ni < 2; _ni++) \
        acc[(mlo) + _mi][(nlo) + _ni] = __builtin_amdgcn_mfma_f32_16x16x32_bf16( \
            a[(mlo) + _mi][_ks], b[(nlo) + _ni][_ks], acc[(mlo) + _mi][(nlo) + _ni], \
            0, 0, 0); \
    __builtin_amdgcn_s_setprio(0); \
} while (0)

template <int MODE>
__global__ __launch_bounds__(512, 2) void gemm256(
    const bf16* __restrict__ A, int lda,
    const bf16* __restrict__ Bt, int ldb,
    void* __restrict__ Cv, int ldc,
    int K, float alpha,
    const float* __restrict__ res, const int* __restrict__ selp,
    const float* __restrict__ rwp, float* __restrict__ outp) {
    __shared__ char smem[131072];   // buf c: A @ c*65536, B @ c*65536+32768

    const int tid = threadIdx.x;
    const int lane = tid & 63;
    const int wid = tid >> 6;
    const int wm = wid >> 2, wn = wid & 3;     // 2 x 4 waves
    const int lm = lane & 15, lq = lane >> 4;

    // XCD-bijective block swizzle (all grids have nwg % 8 == 0)
    const int nx = gridDim.x;
    const int nwg = nx * gridDim.y;
    const int orig = blockIdx.y * nx + blockIdx.x;
    const int swz = (orig & 7) * (nwg >> 3) + (orig >> 3);
    const int m0 = (swz / nx) * 256;
    const int n0 = (swz % nx) * 256;
    const long long kz = (long long)blockIdx.z * K;

    // staging: thread stages 16B chunk (row = chunk*64 + tid>>3, kchunk = tid&7);
    // LDS linear, global source pre-swizzled: kc_src = (tid&7) ^ (row&7)
    const int srow = tid >> 3;
    const int skc = ((tid & 7) ^ (srow & 7)) * 8;
    const bf16* gA = A + (long long)(m0 + srow) * lda + kz + skc;
    const bf16* gB = Bt + (long long)(n0 + srow) * ldb + kz + skc;
    const long long stA = (long long)64 * lda;
    const long long stB = (long long)64 * ldb;

    char* sm = (char*)smem;
    const int sdst = tid * 16;

    // frag read offsets: row*128 + ((ks*4+lq) ^ (lm&7))*16 ; ks=1 is ^64
    // (row&7 == lm&7 since all other row terms are multiples of 8)
    const int aoff = (wm * 128 + lm) * 128 + ((lq ^ (lm & 7)) << 4);
    const int boff = (wn * 64 + lm) * 128 + ((lq ^ (lm & 7)) << 4);

    f32x4 acc[8][4];
#pragma unroll
    for (int i = 0; i < 8; i++)
#pragma unroll
        for (int j = 0; j < 4; j++) {
            f32x4 zz = {0.f, 0.f, 0.f, 0.f};
            acc[i][j] = zz;
        }
    bf16x8 a[8][2], b[4][2];

    const int NTk = K >> 6;   // even, >= 16 for all launches here

    // prologue: A(0) full, B(0) full, A(1) full = 12 loads; wait tile0 (8 oldest)
    STAGE_A(0, 0, 0); STAGE_A(0, 1, 0);
    STAGE_B(0, 0, 0); STAGE_B(0, 1, 0);
    STAGE_A(1, 0, 1); STAGE_A(1, 1, 1);
    G256_VMC(4);
    G256_BAR();

    for (int t0 = 0; t0 < NTk; t0 += 2) {
        const int t1 = t0 + 1, t2 = t0 + 2, t3 = t0 + 3;
        const bool more = (t2 < NTk);

        // ---- K-tile t0 (buf 0) ----
        // P1: quadrant (miL,niL)
        LDA_HALF(0, 0); LDB_HALF(0, 0);
        STAGE_B(1, 0, t1);
        G256_BAR(); G256_LGKM0(); MFMA_Q(0, 0); G256_BAR();
        // P2: (miH,niL)
        LDA_HALF(0, 4);
        STAGE_B(1, 1, t1);
        G256_BAR(); G256_LGKM0(); MFMA_Q(4, 0); G256_BAR();
        // P3: (miL,niH)
        LDB_HALF(0, 2);
        if (more) STAGE_A(0, 0, t2);
        G256_BAR(); G256_LGKM0(); MFMA_Q(0, 2); G256_BAR();
        // P4: (miH,niH); vmcnt before trailing barrier
        if (more) STAGE_A(0, 1, t2);
        G256_BAR(); G256_LGKM0(); MFMA_Q(4, 2);
        if (more) { G256_VMC(4); } else { G256_VMC(0); }
        G256_BAR();

        // ---- K-tile t1 (buf 1) ----
        // P5
        LDA_HALF(1, 0); LDB_HALF(1, 0);
        if (more) STAGE_B(0, 0, t2);
        G256_BAR(); G256_LGKM0(); MFMA_Q(0, 0); G256_BAR();
        // P6
        LDA_HALF(1, 4);
        if (more) STAGE_B(0, 1, t2);
        G256_BAR(); G256_LGKM0(); MFMA_Q(4, 0); G256_BAR();
        // P7
        LDB_HALF(1, 2);
        if (more) STAGE_A(1, 0, t3);
        G256_BAR(); G256_LGKM0(); MFMA_Q(0, 2); G256_BAR();
        // P8
        if (more) STAGE_A(1, 1, t3);
        G256_BAR(); G256_LGKM0(); MFMA_Q(4, 2);
        if (more) { G256_VMC(4); } else { G256_VMC(0); }
        G256_BAR();
    }

#pragma unroll
    for (int mi = 0; mi < 8; mi++) {
#pragma unroll
        for (int ni = 0; ni < 4; ni++) {
            const int row = m0 + wm * 128 + mi * 16 + lq * 4;
            const int col = n0 + wn * 64 + ni * 16 + lm;
#pragma unroll
            for (int r = 0; r < 4; r++) {
                float v = alpha * acc[mi][ni][r];
                long long rr = row + r;
                if constexpr (MODE == 0) {
                    bf16* C = (bf16*)Cv;
                    C[rr * ldc + col] = (bf16)v;
                } else if constexpr (MODE == 2) {
                    float* C = (float*)Cv;
                    unsafeAtomicAdd(&C[rr * ldc + col], v);
                } else if constexpr (MODE == 3) {
                    bf16* C = (bf16*)Cv;
                    C[rr * ldc + col] = (bf16)(v / (1.f + __expf(-v)));
                } else if constexpr (MODE == 4) {
                    bf16* C = (bf16*)Cv;
                    bf16* p = &C[rr * ldc + col];
                    *p = (bf16)((float)*p * v);
                } else {   // MODE 5
                    int bb2 = (int)(rr >> 10);
                    int s = selp[rr];
                    float add = rwp[rr] *
                        (v + (blockIdx.z == 0 ? res[rr * (long long)ND + col] : 0.f));
                    unsafeAtomicAdd(outp + ((long long)bb2 * NS + s) * ND + col, add);
                }
            }
        }
    }
}

// ---------------------------------------------------------------------------
extern "C" void kernel_launch(void* const* d_in, const int* in_sizes, int n_in,
                              void* d_out, int out_size, void* d_ws, size_t ws_size,
                              hipStream_t stream) {
    const float* x  = (const float*)d_in[0];
    const float* fr = (const float*)d_in[2];
    const float* wr = (const float*)d_in[3];
    const float* g1 = (const float*)d_in[4];
    const float* wq = (const float*)d_in[5];
    const float* wk = (const float*)d_in[6];
    const float* wv = (const float*)d_in[7];
    const float* wo = (const float*)d_in[8];
    const float* g2 = (const float*)d_in[9];
    const float* w1 = (const float*)d_in[10];
    const float* w3 = (const float*)d_in[11];
    const float* w2 = (const float*)d_in[12];
    float* out = (float*)d_out;

    char* ws = (char*)d_ws;
    size_t off = 0;
    auto take = [&](size_t bytes) -> char* {
        char* p = ws + off;
        off += (bytes + 255) & ~(size_t)255;
        return p;
    };
    int*   sel    = (int*)take((size_t)NB * NT * 4);
    float* rw     = (float*)take((size_t)NB * NT * 4);
    float* logits = (float*)take((size_t)NB * NS * 4);
    float* xf     = (float*)take((size_t)NB * NT * ND * 4);
    bf16*  hbuf   = (bf16*)take((size_t)NB * NT * ND * 2);
    bf16*  wqkv_t = (bf16*)take((size_t)3 * ND * ND * 2);
    bf16*  wo_t   = (bf16*)take((size_t)ND * ND * 2);
    bf16*  Obuf   = (bf16*)take((size_t)NB * NT * ND * 2);
    char* xr = ws + off;
    // attention-phase overlay
    bf16* QKV = (bf16*)xr;                               // [4096][6144]
    bf16* Qr  = QKV + (size_t)NB * NT * 3 * ND;
    bf16* Kr  = Qr + (size_t)NB * NT * ND;
    bf16* Vt  = Kr + (size_t)NB * NT * ND;
    float* scores = (float*)(Vt + (size_t)NB * NT * ND);
    bf16*  P      = (bf16*)(scores + (size_t)NH * NT * NT);
    // FFN-phase overlay (attention data dead by then)
    bf16* w1_t  = (bf16*)xr;
    bf16* w3_t  = w1_t + (size_t)ND * NF;
    bf16* w2_t  = w3_t + (size_t)ND * NF;
    bf16* inter = w2_t + (size_t)ND * NF;

    router_k<<<NB * NS, 256, 0, stream>>>(x, wr, logits);
    topk_k<<<NB, 1024, 0, stream>>>(logits, sel, rw);
    gather_k<<<(NB * NT * ND / 4) / 256, 256, 0, stream>>>(x, sel, xf);
    rmsnorm_k<<<NB * NT, 256, 0, stream>>>(xf, g1, hbuf);

    dim3 tg(ND / 32, ND / 32);
    transpose_to_bf16<<<tg, 256, 0, stream>>>(wq, wqkv_t, ND, ND);
    transpose_to_bf16<<<tg, 256, 0, stream>>>(wk, wqkv_t + (size_t)ND * ND, ND, ND);
    transpose_to_bf16<<<tg, 256, 0, stream>>>(wv, wqkv_t + (size_t)2 * ND * ND, ND, ND);
    transpose_to_bf16<<<tg, 256, 0, stream>>>(wo, wo_t, ND, ND);

    // fused QKV: [4096 x 2048] x [6144 x 2048]^T -> [4096][6144]
    gemm256<0><<<dim3(3 * ND / 256, NB * NT / 256, 1), 512, 0, stream>>>(
        hbuf, ND, wqkv_t, ND, QKV, 3 * ND, ND, 1.0f,
        nullptr, nullptr, nullptr, nullptr);

    rope_k<<<(NB * NT * NH * 64) / 256, 256, 0, stream>>>(QKV, fr, Qr, Kr, Vt);

    const float scal = 0.08838834764831845f;   // 1/sqrt(128)
    for (int bb = 0; bb < NB; bb++) {
        dim3 gs(NT / 128, NT / 128, NH);
        gemm_bt<1><<<gs, 256, 0, stream>>>(
            Qr + (size_t)bb * NH * NT * NHD, NHD, (long long)NT * NHD,
            Kr + (size_t)bb * NH * NT * NHD, NHD, (long long)NT * NHD,
            scores, (long long)NT * NT, NT, NHD, scal,
            nullptr, nullptr, nullptr, nullptr);
        softmax_k<<<NH * NT, 256, 0, stream>>>(scores, P);
        dim3 gv(NHD / 128, NT / 128, NH);
        gemm_bt<0><<<gv, 256, 0, stream>>>(
            P, NT, (long long)NT * NT,
            Vt + (size_t)bb * NH * NHD * NT, NT, (long long)NHD * NT,
            Obuf + (size_t)bb * NT * ND, NHD, ND, NT, 1.0f,
            nullptr, nullptr, nullptr, nullptr);
    }

    // WO: split-K x2 (K=1024 each), atomic += into xf residual
    gemm256<2><<<dim3(ND / 256, NB * NT / 256, 2), 512, 0, stream>>>(
        Obuf, ND, wo_t, ND, xf, ND, ND / 2, 1.0f,
        nullptr, nullptr, nullptr, nullptr);

    rmsnorm_k<<<NB * NT, 256, 0, stream>>>(xf, g2, hbuf);

    transpose_to_bf16<<<dim3(NF / 32, ND / 32), 256, 0, stream>>>(w1, w1_t, ND, NF);
    transpose_to_bf16<<<dim3(NF / 32, ND / 32), 256, 0, stream>>>(w3, w3_t, ND, NF);
    transpose_to_bf16<<<dim3(ND / 32, NF / 32), 256, 0, stream>>>(w2, w2_t, NF, ND);

    dim3 gf(NF / 256, NB * NT / 256, 1);
    gemm256<3><<<gf, 512, 0, stream>>>(hbuf, ND, w1_t, ND, inter, NF, ND, 1.0f,
                                       nullptr, nullptr, nullptr, nullptr);
    gemm256<4><<<gf, 512, 0, stream>>>(hbuf, ND, w3_t, ND, inter, NF, ND, 1.0f,
                                       nullptr, nullptr, nullptr, nullptr);

    copy_k<<<8192, 256, 0, stream>>>((const float4*)x, (float4*)out,
                                     (long long)NB * NS * ND / 4);
    // w2 + scatter-add: split-K x2 (K=4096 each), res added on z==0 only
    gemm256<5><<<dim3(ND / 256, NB * NT / 256, 2), 512, 0, stream>>>(
        inter, NF, w2_t, NF, nullptr, ND, NF / 2, 1.0f, xf, sel, rw, out);
}

// Round 4
// 1479.840 us; speedup vs baseline: 1.0464x; 1.0464x over previous
//
#include <hip/hip_runtime.h>
#include <cstdint>
#include <cstddef>

#define NB 4
#define NS 4096
#define ND 2048
#define NH 16
#define NHD 128
#define NT 1024
#define NF 8192

typedef __bf16 bf16;
typedef __bf16 bf16x8 __attribute__((ext_vector_type(8)));
typedef __bf16 bf16x4 __attribute__((ext_vector_type(4)));
typedef float  f32x4  __attribute__((ext_vector_type(4)));

typedef const __attribute__((address_space(1))) void* gptr_t;
typedef __attribute__((address_space(3))) void* lptr_t;

__device__ __forceinline__ float wave_sum(float v) {
#pragma unroll
    for (int off = 32; off > 0; off >>= 1) v += __shfl_xor(v, off);
    return v;
}
__device__ __forceinline__ float wave_max(float v) {
#pragma unroll
    for (int off = 32; off > 0; off >>= 1) v = fmaxf(v, __shfl_xor(v, off));
    return v;
}

// ---------------------------------------------------------------------------
// Router: logits[row] = dot(x[row,:], w_router)   (row = b*NS+s)
// ---------------------------------------------------------------------------
__global__ __launch_bounds__(256) void router_k(const float* __restrict__ x,
                                                const float* __restrict__ wr,
                                                float* __restrict__ logits) {
    __shared__ float r4[4];
    long long row = blockIdx.x;
    const float4* xr = (const float4*)(x + row * ND);
    const float4* w4 = (const float4*)wr;
    float p = 0.f;
    for (int i = threadIdx.x; i < ND / 4; i += 256) {
        float4 a = xr[i], b = w4[i];
        p += a.x * b.x + a.y * b.y + a.z * b.z + a.w * b.w;
    }
    p = wave_sum(p);
    if ((threadIdx.x & 63) == 0) r4[threadIdx.x >> 6] = p;
    __syncthreads();
    if (threadIdx.x == 0) logits[row] = r4[0] + r4[1] + r4[2] + r4[3];
}

// ---------------------------------------------------------------------------
// Top-K (exact, matches jax.lax.top_k tie-break) + index sort + router softmax.
// ---------------------------------------------------------------------------
__global__ __launch_bounds__(1024) void topk_k(const float* __restrict__ logits,
                                               int* __restrict__ sel,
                                               float* __restrict__ rw) {
    __shared__ unsigned long long keys[NS];   // 32 KB
    __shared__ float r16[16];
    __shared__ float bmax, bsum;
    const int bb = blockIdx.x;
    const int tid = threadIdx.x;
    const float* lg = logits + (long long)bb * NS;

    for (int i = tid; i < NS; i += 1024) {
        unsigned u = __float_as_uint(lg[i]);
        u = (u & 0x80000000u) ? ~u : (u | 0x80000000u);   // order-preserving map
        keys[i] = ((unsigned long long)u << 32) | (unsigned)(NS - 1 - i);
    }
    __syncthreads();
    for (int k = 2; k <= NS; k <<= 1) {
        for (int j = k >> 1; j > 0; j >>= 1) {
            for (int i = tid; i < NS; i += 1024) {
                int ixj = i ^ j;
                if (ixj > i) {
                    unsigned long long a = keys[i], c = keys[ixj];
                    bool up = ((i & k) == 0);
                    if (up ? (a < c) : (a > c)) { keys[i] = c; keys[ixj] = a; }
                }
            }
            __syncthreads();
        }
    }
    unsigned long long a0 = keys[tid];
    __syncthreads();
    {
        unsigned idx_ = NS - 1 - (unsigned)(a0 & 0xFFFFFFFFu);
        unsigned uval = (unsigned)(a0 >> 32);
        keys[tid] = ((unsigned long long)idx_ << 32) | uval;
    }
    __syncthreads();
    for (int k = 2; k <= NT; k <<= 1) {
        for (int j = k >> 1; j > 0; j >>= 1) {
            int i = tid, ixj = i ^ j;
            if (i < NT && ixj > i) {
                unsigned long long a = keys[i], c = keys[ixj];
                bool up = ((i & k) == 0);
                if (up ? (a > c) : (a < c)) { keys[i] = c; keys[ixj] = a; }
            }
            __syncthreads();
        }
    }
    unsigned long long kk = keys[tid];
    int si = (int)(kk >> 32);
    unsigned u = (unsigned)(kk & 0xFFFFFFFFu);
    u = (u & 0x80000000u) ? (u ^ 0x80000000u) : ~u;
    float val = __uint_as_float(u);

    const int wid = tid >> 6, lane = tid & 63;
    float mx = wave_max(val);
    if (lane == 0) r16[wid] = mx;
    __syncthreads();
    if (tid == 0) {
        float m = r16[0];
        for (int i = 1; i < 16; i++) m = fmaxf(m, r16[i]);
        bmax = m;
    }
    __syncthreads();
    float e = __expf(val - bmax);
    float s = wave_sum(e);
    if (lane == 0) r16[wid] = s;
    __syncthreads();
    if (tid == 0) {
        float t = 0.f;
        for (int i = 0; i < 16; i++) t += r16[i];
        bsum = t;
    }
    __syncthreads();
    sel[bb * NT + tid] = si;
    rw[bb * NT + tid] = e / bsum;
}

// ---------------------------------------------------------------------------
// Gather: xf[b,j,:] = x[b, sel[b,j], :]   (float4)
// ---------------------------------------------------------------------------
__global__ __launch_bounds__(256) void gather_k(const float* __restrict__ x,
                                                const int* __restrict__ sel,
                                                float* __restrict__ xf) {
    int gid = blockIdx.x * 256 + threadIdx.x;
    int col = gid & (ND / 4 - 1);
    int row = gid >> 9;
    int bb = row >> 10;
    int s = sel[row];
    ((float4*)xf)[gid] = ((const float4*)x)[((long long)bb * NS + s) * (ND / 4) + col];
}

// ---------------------------------------------------------------------------
// RMSNorm row kernel: out = bf16(x * rsqrt(mean(x^2)+eps) * g)
// ---------------------------------------------------------------------------
__global__ __launch_bounds__(256) void rmsnorm_k(const float* __restrict__ x,
                                                 const float* __restrict__ g,
                                                 bf16* __restrict__ out) {
    __shared__ float r4[4];
    __shared__ float scl;
    long long row = blockIdx.x;
    const float4* xr = (const float4*)(x + row * ND);
    int i0 = threadIdx.x, i1 = threadIdx.x + 256;
    float4 a = xr[i0], b = xr[i1];
    float ss = a.x * a.x + a.y * a.y + a.z * a.z + a.w * a.w +
               b.x * b.x + b.y * b.y + b.z * b.z + b.w * b.w;
    ss = wave_sum(ss);
    if ((threadIdx.x & 63) == 0) r4[threadIdx.x >> 6] = ss;
    __syncthreads();
    if (threadIdx.x == 0)
        scl = rsqrtf((r4[0] + r4[1] + r4[2] + r4[3]) * (1.0f / ND) + 1e-6f);
    __syncthreads();
    float s = scl;
    const float4* g4 = (const float4*)g;
    float4 ga = g4[i0], gb = g4[i1];
    bf16x4 o0, o1;
    o0[0] = (bf16)(a.x * s * ga.x); o0[1] = (bf16)(a.y * s * ga.y);
    o0[2] = (bf16)(a.z * s * ga.z); o0[3] = (bf16)(a.w * s * ga.w);
    o1[0] = (bf16)(b.x * s * gb.x); o1[1] = (bf16)(b.y * s * gb.y);
    o1[2] = (bf16)(b.z * s * gb.z); o1[3] = (bf16)(b.w * s * gb.w);
    *(bf16x4*)(out + row * ND + i0 * 4) = o0;
    *(bf16x4*)(out + row * ND + i1 * 4) = o1;
}

// ---------------------------------------------------------------------------
// Transpose + fp32->bf16: out[c][r] = in[r][c]; in is R x C. dims %32 == 0.
// ---------------------------------------------------------------------------
__global__ __launch_bounds__(256) void transpose_to_bf16(const float* __restrict__ in,
                                                         bf16* __restrict__ out,
                                                         int R, int C) {
    __shared__ float tile[32][33];
    int bx = blockIdx.x * 32;   // col
    int by = blockIdx.y * 32;   // row
    int tx = threadIdx.x & 31;
    int ty = threadIdx.x >> 5;   // 0..7
#pragma unroll
    for (int i = 0; i < 4; i++)
        tile[ty + 8 * i][tx] = in[(long long)(by + ty + 8 * i) * C + bx + tx];
    __syncthreads();
#pragma unroll
    for (int i = 0; i < 4; i++)
        out[(long long)(bx + ty + 8 * i) * R + by + tx] = (bf16)tile[tx][ty + 8 * i];
}

// ---------------------------------------------------------------------------
// RoPE + layout shuffle (reads fused QKV buffer, row stride 3*ND)
// ---------------------------------------------------------------------------
__global__ __launch_bounds__(256) void rope_k(const bf16* __restrict__ QKV,
                                              const float* __restrict__ fr,
                                              bf16* __restrict__ Q,
                                              bf16* __restrict__ K,
                                              bf16* __restrict__ Vt) {
    int gid = blockIdx.x * 256 + threadIdx.x;
    int hd = gid & 63;
    int h = (gid >> 6) & 15;
    int t = (gid >> 10) & (NT - 1);
    int bb = gid >> 20;
    float c = fr[t * 128 + hd * 2 + 0];
    float s = fr[t * 128 + hd * 2 + 1];
    long long base = ((long long)bb * NT + t) * (3 * ND) + h * NHD;
    float q1 = (float)QKV[base + hd],      q2 = (float)QKV[base + hd + 64];
    float k1 = (float)QKV[base + ND + hd], k2 = (float)QKV[base + ND + hd + 64];
    long long ob = (((long long)(bb * NH + h)) * NT + t) * NHD;
    Q[ob + hd]      = (bf16)(q1 * c - q2 * s);
    Q[ob + hd + 64] = (bf16)(q1 * s + q2 * c);
    K[ob + hd]      = (bf16)(k1 * c - k2 * s);
    K[ob + hd + 64] = (bf16)(k1 * s + k2 * c);
    long long vb = ((long long)(bb * NH + h)) * NHD * NT + t;
    Vt[vb + (long long)hd * NT]        = QKV[base + 2 * ND + hd];
    Vt[vb + (long long)(hd + 64) * NT] = QKV[base + 2 * ND + hd + 64];
}

// ---------------------------------------------------------------------------
// Row softmax (T=1024 cols): P = bf16(softmax(scores_row))
// ---------------------------------------------------------------------------
__global__ __launch_bounds__(256) void softmax_k(const float* __restrict__ Sc,
                                                 bf16* __restrict__ P) {
    __shared__ float r4[4];
    __shared__ float bc;
    long long row = blockIdx.x;
    float4 v = ((const float4*)(Sc + row * NT))[threadIdx.x];
    float mx = fmaxf(fmaxf(v.x, v.y), fmaxf(v.z, v.w));
    mx = wave_max(mx);
    if ((threadIdx.x & 63) == 0) r4[threadIdx.x >> 6] = mx;
    __syncthreads();
    if (threadIdx.x == 0) bc = fmaxf(fmaxf(r4[0], r4[1]), fmaxf(r4[2], r4[3]));
    __syncthreads();
    float m = bc;
    float e0 = __expf(v.x - m), e1 = __expf(v.y - m);
    float e2 = __expf(v.z - m), e3 = __expf(v.w - m);
    float ss = wave_sum(e0 + e1 + e2 + e3);
    if ((threadIdx.x & 63) == 0) r4[threadIdx.x >> 6] = ss;
    __syncthreads();
    if (threadIdx.x == 0) bc = 1.f / (r4[0] + r4[1] + r4[2] + r4[3]);
    __syncthreads();
    float inv = bc;
    bf16x4 o;
    o[0] = (bf16)(e0 * inv); o[1] = (bf16)(e1 * inv);
    o[2] = (bf16)(e2 * inv); o[3] = (bf16)(e3 * inv);
    *(bf16x4*)(P + row * NT + threadIdx.x * 4) = o;
}

// ---------------------------------------------------------------------------
__global__ __launch_bounds__(256) void copy_k(const float4* __restrict__ in,
                                              float4* __restrict__ out, long long n) {
    for (long long i = (long long)blockIdx.x * 256 + threadIdx.x; i < n;
         i += (long long)gridDim.x * 256)
        out[i] = in[i];
}

// ---------------------------------------------------------------------------
// MFMA GEMM (m97 structure) — kept for attention shapes (K=128 / N=128).
// MODE 0: C bf16 = alpha*acc     MODE 1: C fp32 = alpha*acc
// ---------------------------------------------------------------------------
template <int MODE>
__global__ __launch_bounds__(256, 2) void gemm_bt(
    const bf16* __restrict__ A, int lda, long long sAz,
    const bf16* __restrict__ Bt, int ldb, long long sBz,
    void* __restrict__ Cv, long long sCz, int ldc,
    int K, float alpha) {
    __shared__ bf16 As[128][32];   // 8 KB, unpadded (global_load_lds layout)
    __shared__ bf16 Bs[128][32];

    const int tid = threadIdx.x;
    const int lane = tid & 63;
    const int wave = tid >> 6;
    const int wm = wave >> 1, wn = wave & 1;
    const int lm = lane & 15, lq = lane >> 4;

    const int m0 = blockIdx.y * 128;
    const int n0 = blockIdx.x * 128;
    const int z = blockIdx.z;

    A += (long long)z * sAz;
    Bt += (long long)z * sBz;

    f32x4 acc[4][4];
#pragma unroll
    for (int i = 0; i < 4; i++)
#pragma unroll
        for (int j = 0; j < 4; j++) {
            f32x4 zz = {0.f, 0.f, 0.f, 0.f};
            acc[i][j] = zz;
        }

    const int sr = wave * 16 + (lane >> 2);
    const int sk = (lane & 3) * 8;
    const bf16* gA0 = A + (long long)(m0 + sr) * lda + sk;
    const bf16* gA1 = gA0 + (long long)64 * lda;
    const bf16* gB0 = Bt + (long long)(n0 + sr) * ldb + sk;
    const bf16* gB1 = gB0 + (long long)64 * ldb;
    bf16* lA0 = &As[sr][sk];
    bf16* lA1 = &As[sr + 64][sk];
    bf16* lB0 = &Bs[sr][sk];
    bf16* lB1 = &Bs[sr + 64][sk];

    for (int k0 = 0; k0 < K; k0 += 32) {
        __builtin_amdgcn_global_load_lds((gptr_t)(gA0 + k0), (lptr_t)lA0, 16, 0, 0);
        __builtin_amdgcn_global_load_lds((gptr_t)(gA1 + k0), (lptr_t)lA1, 16, 0, 0);
        __builtin_amdgcn_global_load_lds((gptr_t)(gB0 + k0), (lptr_t)lB0, 16, 0, 0);
        __builtin_amdgcn_global_load_lds((gptr_t)(gB1 + k0), (lptr_t)lB1, 16, 0, 0);
        __syncthreads();

        bf16x8 af[4], bfr[4];
#pragma unroll
        for (int mi = 0; mi < 4; mi++)
            af[mi] = *(const bf16x8*)&As[wm * 64 + mi * 16 + lm][lq * 8];
#pragma unroll
        for (int ni = 0; ni < 4; ni++)
            bfr[ni] = *(const bf16x8*)&Bs[wn * 64 + ni * 16 + lm][lq * 8];
#pragma unroll
        for (int mi = 0; mi < 4; mi++)
#pragma unroll
            for (int ni = 0; ni < 4; ni++)
                acc[mi][ni] = __builtin_amdgcn_mfma_f32_16x16x32_bf16(
                    af[mi], bfr[ni], acc[mi][ni], 0, 0, 0);
        __syncthreads();
    }

#pragma unroll
    for (int mi = 0; mi < 4; mi++) {
#pragma unroll
        for (int ni = 0; ni < 4; ni++) {
            int row = m0 + wm * 64 + mi * 16 + lq * 4;
            int col = n0 + wn * 64 + ni * 16 + lm;
#pragma unroll
            for (int r = 0; r < 4; r++) {
                float v = alpha * acc[mi][ni][r];
                long long rr = row + r;
                if constexpr (MODE == 0) {
                    bf16* C = (bf16*)Cv + (long long)z * sCz;
                    C[rr * ldc + col] = (bf16)v;
                } else {
                    float* C = (float*)Cv + (long long)z * sCz;
                    C[rr * ldc + col] = v;
                }
            }
        }
    }
}

// ---------------------------------------------------------------------------
// 256-wide 8-phase pipelined GEMM (T2+T3+T4+T5), L2-aware 2D XCD mapping.
//   All launches have gridDim.y == 16 (M=4096). Grid is split into a 2x4
//   super-grid of per-XCD quadrants; within an XCD blocks walk an
//   8 x (nx/4) rect M-first, so the ~32 concurrent blocks of an XCD touch
//   8 A-panels + <=4 B-panels (L2 working set ~12 MB vs 34 MB row-major).
//   MODE 0: C bf16 = alpha*acc (256-N tile)
//   MODE 2: C fp32 atomic += acc (256-N, split-K via blockIdx.z)
//   MODE 5: out[(b*NS+sel[m])*ND+n] atomic += rw[m]*(acc+(z==0)*res) (256-N)
//   MODE 6: dual-B (Bt=w1_t, Bt2=w3_t), 128-N tile per matrix;
//           C bf16 = silu(acc1)*acc3  (fused FFN up-projection)
// ---------------------------------------------------------------------------
#define G256_BAR() do { __builtin_amdgcn_sched_barrier(0); \
    __builtin_amdgcn_s_barrier(); __builtin_amdgcn_sched_barrier(0); } while (0)
#define G256_LGKM0() do { asm volatile("s_waitcnt lgkmcnt(0)" ::: "memory"); \
    __builtin_amdgcn_sched_barrier(0); } while (0)
#define G256_VMC(n) do { asm volatile("s_waitcnt vmcnt(" #n ")" ::: "memory"); \
    __builtin_amdgcn_sched_barrier(0); } while (0)

#define STAGE_A(c, h, t) do { \
    char* _l = sm + (c) * 65536 + (h) * 16384 + sdst; \
    long long _ko = (long long)(t) * 64; \
    __builtin_amdgcn_global_load_lds((gptr_t)(gA + (2 * (h)) * stA + _ko), \
                                     (lptr_t)_l, 16, 0, 0); \
    __builtin_amdgcn_global_load_lds((gptr_t)(gA + (2 * (h) + 1) * stA + _ko), \
                                     (lptr_t)(_l + 8192), 16, 0, 0); \
} while (0)
#define STAGE_B(c, h, t) do { \
    char* _l = sm + (c) * 65536 + 32768 + (h) * 16384 + sdst; \
    long long _ko = (long long)(t) * 64; \
    const bf16* _g = (h) ? gBhi : gBlo; \
    __builtin_amdgcn_global_load_lds((gptr_t)(_g + _ko), \
                                     (lptr_t)_l, 16, 0, 0); \
    __builtin_amdgcn_global_load_lds((gptr_t)(_g + stB + _ko), \
                                     (lptr_t)(_l + 8192), 16, 0, 0); \
} while (0)

#define LDA_HALF(c, lo) do { \
    char* _b = sm + (c) * 65536; \
    _Pragma("unroll") \
    for (int _mi = 0; _mi < 4; _mi++) { \
        a[(lo) + _mi][0] = *(const bf16x8*)(_b + aoff + ((lo) + _mi) * 2048); \
        a[(lo) + _mi][1] = *(const bf16x8*)(_b + (aoff ^ 64) + ((lo) + _mi) * 2048); \
    } \
} while (0)
#define LDB_HALF(c, lo) do { \
    char* _b = sm + (c) * 65536 + 32768; \
    _Pragma("unroll") \
    for (int _ni = 0; _ni < 2; _ni++) { \
        int _ix = (lo) + _ni; \
        int _o = boff + (_ix & 1) * 2048 + (_ix >> 1) * bStep2; \
        b[_ix][0] = *(const bf16x8*)(_b + _o); \
        b[_ix][1] = *(const bf16x8*)(_b + (_o ^ 64)); \
    } \
} while (0)

#define MFMA_Q(mlo, nlo) do { \
    __builtin_amdgcn_s_setprio(1); \
    _Pragma("unroll") \
    for (int _ks = 0; _ks < 2; _ks++) \
    _Pragma("unroll") \
    for (int _mi = 0; _mi < 4; _mi++) \
    _Pragma("unroll") \
    for (int _ni = 0; _ni < 2; _ni++) \
        acc[(mlo) + _mi][(nlo) + _ni] = __builtin_amdgcn_mfma_f32_16x16x32_bf16( \
            a[(mlo) + _mi][_ks], b[(nlo) + _ni][_ks], acc[(mlo) + _mi][(nlo) + _ni], \
            0, 0, 0); \
    __builtin_amdgcn_s_setprio(0); \
} while (0)

template <int MODE>
__global__ __launch_bounds__(512, 2) void gemm256(
    const bf16* __restrict__ A, int lda,
    const bf16* __restrict__ Bt, int ldb,
    void* __restrict__ Cv, int ldc,
    int K, float alpha,
    const bf16* __restrict__ Bt2,
    const float* __restrict__ res, const int* __restrict__ selp,
    const float* __restrict__ rwp, float* __restrict__ outp) {
    __shared__ char smem[131072];   // buf c: A @ c*65536, B @ c*65536+32768

    constexpr bool DUALB = (MODE == 6);
    constexpr int bStep2 = DUALB ? 16384 : 4096;   // byte offset ni=2 vs ni=0

    const int tid = threadIdx.x;
    const int lane = tid & 63;
    const int wid = tid >> 6;
    const int wm = wid >> 2, wn = wid & 3;     // 2 x 4 waves
    const int lm = lane & 15, lq = lane >> 4;

    // 2D XCD mapping: xcd quadrant (2 in M x 4 in N), 8 x (nx/4) rect inside,
    // M-first so concurrent blocks share B panels. Requires ny==16, nx%4==0.
    const int nx = gridDim.x;
    const int orig = blockIdx.y * nx + blockIdx.x;
    const int xcd = orig & 7;
    const int r_ = orig >> 3;                  // [0, 2*nx)
    const int mi_ = r_ & 7, ni_ = r_ >> 3;     // 8 x (nx/4)
    const int nTile = DUALB ? 128 : 256;
    const int m0 = ((xcd >> 2) * 8 + mi_) * 256;
    const int n0 = ((xcd & 3) * (nx >> 2) + ni_) * nTile;
    const long long kz = (long long)blockIdx.z * K;

    // staging: thread stages 16B chunk (row = chunk*64 + tid>>3, kchunk = tid&7);
    // LDS linear, global source pre-swizzled: kc_src = (tid&7) ^ (row&7)
    const int srow = tid >> 3;                 // [0,64)
    const int skc = ((tid & 7) ^ (srow & 7)) * 8;
    const bf16* gA = A + (long long)(m0 + srow) * lda + kz + skc;
    // B rows: LDS rows 0..127 <- Bt[n0+srow(+64)], rows 128..255 <-
    //   DUALB ? Bt2[n0+srow(+64)] : Bt[n0+128+srow(+64)]
    const bf16* gBlo = Bt + (long long)(n0 + srow) * ldb + kz + skc;
    const bf16* gBhi = DUALB
        ? Bt2 + (long long)(n0 + srow) * ldb + kz + skc
        : gBlo + (long long)128 * ldb;
    const long long stA = (long long)64 * lda;
    const long long stB = (long long)64 * ldb;

    char* sm = (char*)smem;
    const int sdst = tid * 16;

    // frag read offsets: row*128 + ((ks*4+lq) ^ (lm&7))*16 ; ks=1 is ^64
    // (row&7 == lm&7 since all other row terms are multiples of 8)
    const int aoff = (wm * 128 + lm) * 128 + ((lq ^ (lm & 7)) << 4);
    const int boff = ((DUALB ? wn * 32 : wn * 64) + lm) * 128 + ((lq ^ (lm & 7)) << 4);

    f32x4 acc[8][4];
#pragma unroll
    for (int i = 0; i < 8; i++)
#pragma unroll
        for (int j = 0; j < 4; j++) {
            f32x4 zz = {0.f, 0.f, 0.f, 0.f};
            acc[i][j] = zz;
        }
    bf16x8 a[8][2], b[4][2];

    const int NTk = K >> 6;   // even, >= 16 for all launches here

    // prologue: A(0) full, B(0) full, A(1) full = 12 loads; wait tile0 (8 oldest)
    STAGE_A(0, 0, 0); STAGE_A(0, 1, 0);
    STAGE_B(0, 0, 0); STAGE_B(0, 1, 0);
    STAGE_A(1, 0, 1); STAGE_A(1, 1, 1);
    G256_VMC(4);
    G256_BAR();

    for (int t0 = 0; t0 < NTk; t0 += 2) {
        const int t1 = t0 + 1, t2 = t0 + 2, t3 = t0 + 3;
        const bool more = (t2 < NTk);

        // ---- K-tile t0 (buf 0) ----
        LDA_HALF(0, 0); LDB_HALF(0, 0);
        STAGE_B(1, 0, t1);
        G256_BAR(); G256_LGKM0(); MFMA_Q(0, 0); G256_BAR();
        LDA_HALF(0, 4);
        STAGE_B(1, 1, t1);
        G256_BAR(); G256_LGKM0(); MFMA_Q(4, 0); G256_BAR();
        LDB_HALF(0, 2);
        if (more) STAGE_A(0, 0, t2);
        G256_BAR(); G256_LGKM0(); MFMA_Q(0, 2); G256_BAR();
        if (more) STAGE_A(0, 1, t2);
        G256_BAR(); G256_LGKM0(); MFMA_Q(4, 2);
        if (more) { G256_VMC(4); } else { G256_VMC(0); }
        G256_BAR();

        // ---- K-tile t1 (buf 1) ----
        LDA_HALF(1, 0); LDB_HALF(1, 0);
        if (more) STAGE_B(0, 0, t2);
        G256_BAR(); G256_LGKM0(); MFMA_Q(0, 0); G256_BAR();
        LDA_HALF(1, 4);
        if (more) STAGE_B(0, 1, t2);
        G256_BAR(); G256_LGKM0(); MFMA_Q(4, 0); G256_BAR();
        LDB_HALF(1, 2);
        if (more) STAGE_A(1, 0, t3);
        G256_BAR(); G256_LGKM0(); MFMA_Q(0, 2); G256_BAR();
        if (more) STAGE_A(1, 1, t3);
        G256_BAR(); G256_LGKM0(); MFMA_Q(4, 2);
        if (more) { G256_VMC(4); } else { G256_VMC(0); }
        G256_BAR();
    }

    if constexpr (MODE == 6) {
        // pair acc[mi][ni] (w1) with acc[mi][ni+2] (w3): same (row,col)
        bf16* C = (bf16*)Cv;
#pragma unroll
        for (int mi = 0; mi < 8; mi++) {
#pragma unroll
            for (int ni = 0; ni < 2; ni++) {
                const int row = m0 + wm * 128 + mi * 16 + lq * 4;
                const int col = n0 + wn * 32 + ni * 16 + lm;
#pragma unroll
                for (int r = 0; r < 4; r++) {
                    float v1 = acc[mi][ni][r];
                    float v3 = acc[mi][ni + 2][r];
                    C[(long long)(row + r) * ldc + col] =
                        (bf16)((v1 / (1.f + __expf(-v1))) * v3);
                }
            }
        }
    } else {
#pragma unroll
        for (int mi = 0; mi < 8; mi++) {
#pragma unroll
            for (int ni = 0; ni < 4; ni++) {
                const int row = m0 + wm * 128 + mi * 16 + lq * 4;
                const int col = n0 + wn * 64 + ni * 16 + lm;
#pragma unroll
                for (int r = 0; r < 4; r++) {
                    float v = alpha * acc[mi][ni][r];
                    long long rr = row + r;
                    if constexpr (MODE == 0) {
                        bf16* C = (bf16*)Cv;
                        C[rr * ldc + col] = (bf16)v;
                    } else if constexpr (MODE == 2) {
                        float* C = (float*)Cv;
                        unsafeAtomicAdd(&C[rr * ldc + col], v);
                    } else {   // MODE 5
                        int bb2 = (int)(rr >> 10);
                        int s = selp[rr];
                        float add = rwp[rr] *
                            (v + (blockIdx.z == 0 ? res[rr * (long long)ND + col] : 0.f));
                        unsafeAtomicAdd(outp + ((long long)bb2 * NS + s) * ND + col, add);
                    }
                }
            }
        }
    }
}

// ---------------------------------------------------------------------------
extern "C" void kernel_launch(void* const* d_in, const int* in_sizes, int n_in,
                              void* d_out, int out_size, void* d_ws, size_t ws_size,
                              hipStream_t stream) {
    const float* x  = (const float*)d_in[0];
    const float* fr = (const float*)d_in[2];
    const float* wr = (const float*)d_in[3];
    const float* g1 = (const float*)d_in[4];
    const float* wq = (const float*)d_in[5];
    const float* wk = (const float*)d_in[6];
    const float* wv = (const float*)d_in[7];
    const float* wo = (const float*)d_in[8];
    const float* g2 = (const float*)d_in[9];
    const float* w1 = (const float*)d_in[10];
    const float* w3 = (const float*)d_in[11];
    const float* w2 = (const float*)d_in[12];
    float* out = (float*)d_out;

    char* ws = (char*)d_ws;
    size_t off = 0;
    auto take = [&](size_t bytes) -> char* {
        char* p = ws + off;
        off += (bytes + 255) & ~(size_t)255;
        return p;
    };
    int*   sel    = (int*)take((size_t)NB * NT * 4);
    float* rw     = (float*)take((size_t)NB * NT * 4);
    float* logits = (float*)take((size_t)NB * NS * 4);
    float* xf     = (float*)take((size_t)NB * NT * ND * 4);
    bf16*  hbuf   = (bf16*)take((size_t)NB * NT * ND * 2);
    bf16*  wqkv_t = (bf16*)take((size_t)3 * ND * ND * 2);
    bf16*  wo_t   = (bf16*)take((size_t)ND * ND * 2);
    bf16*  Obuf   = (bf16*)take((size_t)NB * NT * ND * 2);
    char* xr = ws + off;
    // attention-phase overlay
    bf16* QKV = (bf16*)xr;                               // [4096][6144]
    bf16* Qr  = QKV + (size_t)NB * NT * 3 * ND;
    bf16* Kr  = Qr + (size_t)NB * NT * ND;
    bf16* Vt  = Kr + (size_t)NB * NT * ND;
    float* scores = (float*)(Vt + (size_t)NB * NT * ND);
    bf16*  P      = (bf16*)(scores + (size_t)NH * NT * NT);
    // FFN-phase overlay (attention data dead by then)
    bf16* w1_t  = (bf16*)xr;
    bf16* w3_t  = w1_t + (size_t)ND * NF;
    bf16* w2_t  = w3_t + (size_t)ND * NF;
    bf16* inter = w2_t + (size_t)ND * NF;

    router_k<<<NB * NS, 256, 0, stream>>>(x, wr, logits);
    topk_k<<<NB, 1024, 0, stream>>>(logits, sel, rw);
    gather_k<<<(NB * NT * ND / 4) / 256, 256, 0, stream>>>(x, sel, xf);
    rmsnorm_k<<<NB * NT, 256, 0, stream>>>(xf, g1, hbuf);

    dim3 tg(ND / 32, ND / 32);
    transpose_to_bf16<<<tg, 256, 0, stream>>>(wq, wqkv_t, ND, ND);
    transpose_to_bf16<<<tg, 256, 0, stream>>>(wk, wqkv_t + (size_t)ND * ND, ND, ND);
    transpose_to_bf16<<<tg, 256, 0, stream>>>(wv, wqkv_t + (size_t)2 * ND * ND, ND, ND);
    transpose_to_bf16<<<tg, 256, 0, stream>>>(wo, wo_t, ND, ND);

    // fused QKV: [4096 x 2048] x [6144 x 2048]^T -> [4096][6144]
    gemm256<0><<<dim3(3 * ND / 256, NB * NT / 256, 1), 512, 0, stream>>>(
        hbuf, ND, wqkv_t, ND, QKV, 3 * ND, ND, 1.0f,
        nullptr, nullptr, nullptr, nullptr, nullptr);

    rope_k<<<(NB * NT * NH * 64) / 256, 256, 0, stream>>>(QKV, fr, Qr, Kr, Vt);

    const float scal = 0.08838834764831845f;   // 1/sqrt(128)
    for (int bb = 0; bb < NB; bb++) {
        dim3 gs(NT / 128, NT / 128, NH);
        gemm_bt<1><<<gs, 256, 0, stream>>>(
            Qr + (size_t)bb * NH * NT * NHD, NHD, (long long)NT * NHD,
            Kr + (size_t)bb * NH * NT * NHD, NHD, (long long)NT * NHD,
            scores, (long long)NT * NT, NT, NHD, scal);
        softmax_k<<<NH * NT, 256, 0, stream>>>(scores, P);
        dim3 gv(NHD / 128, NT / 128, NH);
        gemm_bt<0><<<gv, 256, 0, stream>>>(
            P, NT, (long long)NT * NT,
            Vt + (size_t)bb * NH * NHD * NT, NT, (long long)NHD * NT,
            Obuf + (size_t)bb * NT * ND, NHD, ND, NT, 1.0f);
    }

    // WO: split-K x2 (K=1024 each), atomic += into xf residual
    gemm256<2><<<dim3(ND / 256, NB * NT / 256, 2), 512, 0, stream>>>(
        Obuf, ND, wo_t, ND, xf, ND, ND / 2, 1.0f,
        nullptr, nullptr, nullptr, nullptr, nullptr);

    rmsnorm_k<<<NB * NT, 256, 0, stream>>>(xf, g2, hbuf);

    transpose_to_bf16<<<dim3(NF / 32, ND / 32), 256, 0, stream>>>(w1, w1_t, ND, NF);
    transpose_to_bf16<<<dim3(NF / 32, ND / 32), 256, 0, stream>>>(w3, w3_t, ND, NF);
    transpose_to_bf16<<<dim3(ND / 32, NF / 32), 256, 0, stream>>>(w2, w2_t, NF, ND);

    // fused FFN up: inter = silu(h.w1) * (h.w3), one dual-B dispatch
    gemm256<6><<<dim3(NF / 128, NB * NT / 256, 1), 512, 0, stream>>>(
        hbuf, ND, w1_t, ND, inter, NF, ND, 1.0f,
        w3_t, nullptr, nullptr, nullptr, nullptr);

    copy_k<<<8192, 256, 0, stream>>>((const float4*)x, (float4*)out,
                                     (long long)NB * NS * ND / 4);
    // w2 + scatter-add: split-K x2 (K=4096 each), res added on z==0 only
    gemm256<5><<<dim3(ND / 256, NB * NT / 256, 2), 512, 0, stream>>>(
        inter, NF, w2_t, NF, nullptr, ND, NF / 2, 1.0f,
        nullptr, xf, sel, rw, out);
}

// Round 5
// 1322.538 us; speedup vs baseline: 1.1709x; 1.1189x over previous
//
#include <hip/hip_runtime.h>
#include <cstdint>
#include <cstddef>

#define NB 4
#define NS 4096
#define ND 2048
#define NH 16
#define NHD 128
#define NT 1024
#define NF 8192

typedef __bf16 bf16;
typedef __bf16 bf16x8 __attribute__((ext_vector_type(8)));
typedef __bf16 bf16x4 __attribute__((ext_vector_type(4)));
typedef float  f32x4  __attribute__((ext_vector_type(4)));

typedef const __attribute__((address_space(1))) void* gptr_t;
typedef __attribute__((address_space(3))) void* lptr_t;

__device__ __forceinline__ float wave_sum(float v) {
#pragma unroll
    for (int off = 32; off > 0; off >>= 1) v += __shfl_xor(v, off);
    return v;
}
__device__ __forceinline__ float wave_max(float v) {
#pragma unroll
    for (int off = 32; off > 0; off >>= 1) v = fmaxf(v, __shfl_xor(v, off));
    return v;
}

// ---------------------------------------------------------------------------
// Router: logits[row] = dot(x[row,:], w_router)   (row = b*NS+s)
// ---------------------------------------------------------------------------
__global__ __launch_bounds__(256) void router_k(const float* __restrict__ x,
                                                const float* __restrict__ wr,
                                                float* __restrict__ logits) {
    __shared__ float r4[4];
    long long row = blockIdx.x;
    const float4* xr = (const float4*)(x + row * ND);
    const float4* w4 = (const float4*)wr;
    float p = 0.f;
    for (int i = threadIdx.x; i < ND / 4; i += 256) {
        float4 a = xr[i], b = w4[i];
        p += a.x * b.x + a.y * b.y + a.z * b.z + a.w * b.w;
    }
    p = wave_sum(p);
    if ((threadIdx.x & 63) == 0) r4[threadIdx.x >> 6] = p;
    __syncthreads();
    if (threadIdx.x == 0) logits[row] = r4[0] + r4[1] + r4[2] + r4[3];
}

// ---------------------------------------------------------------------------
// Top-K (exact, matches jax.lax.top_k tie-break) + index sort + router softmax.
// ---------------------------------------------------------------------------
__global__ __launch_bounds__(1024) void topk_k(const float* __restrict__ logits,
                                               int* __restrict__ sel,
                                               float* __restrict__ rw) {
    __shared__ unsigned long long keys[NS];   // 32 KB
    __shared__ float r16[16];
    __shared__ float bmax, bsum;
    const int bb = blockIdx.x;
    const int tid = threadIdx.x;
    const float* lg = logits + (long long)bb * NS;

    for (int i = tid; i < NS; i += 1024) {
        unsigned u = __float_as_uint(lg[i]);
        u = (u & 0x80000000u) ? ~u : (u | 0x80000000u);   // order-preserving map
        keys[i] = ((unsigned long long)u << 32) | (unsigned)(NS - 1 - i);
    }
    __syncthreads();
    for (int k = 2; k <= NS; k <<= 1) {
        for (int j = k >> 1; j > 0; j >>= 1) {
            for (int i = tid; i < NS; i += 1024) {
                int ixj = i ^ j;
                if (ixj > i) {
                    unsigned long long a = keys[i], c = keys[ixj];
                    bool up = ((i & k) == 0);
                    if (up ? (a < c) : (a > c)) { keys[i] = c; keys[ixj] = a; }
                }
            }
            __syncthreads();
        }
    }
    unsigned long long a0 = keys[tid];
    __syncthreads();
    {
        unsigned idx_ = NS - 1 - (unsigned)(a0 & 0xFFFFFFFFu);
        unsigned uval = (unsigned)(a0 >> 32);
        keys[tid] = ((unsigned long long)idx_ << 32) | uval;
    }
    __syncthreads();
    for (int k = 2; k <= NT; k <<= 1) {
        for (int j = k >> 1; j > 0; j >>= 1) {
            int i = tid, ixj = i ^ j;
            if (i < NT && ixj > i) {
                unsigned long long a = keys[i], c = keys[ixj];
                bool up = ((i & k) == 0);
                if (up ? (a > c) : (a < c)) { keys[i] = c; keys[ixj] = a; }
            }
            __syncthreads();
        }
    }
    unsigned long long kk = keys[tid];
    int si = (int)(kk >> 32);
    unsigned u = (unsigned)(kk & 0xFFFFFFFFu);
    u = (u & 0x80000000u) ? (u ^ 0x80000000u) : ~u;
    float val = __uint_as_float(u);

    const int wid = tid >> 6, lane = tid & 63;
    float mx = wave_max(val);
    if (lane == 0) r16[wid] = mx;
    __syncthreads();
    if (tid == 0) {
        float m = r16[0];
        for (int i = 1; i < 16; i++) m = fmaxf(m, r16[i]);
        bmax = m;
    }
    __syncthreads();
    float e = __expf(val - bmax);
    float s = wave_sum(e);
    if (lane == 0) r16[wid] = s;
    __syncthreads();
    if (tid == 0) {
        float t = 0.f;
        for (int i = 0; i < 16; i++) t += r16[i];
        bsum = t;
    }
    __syncthreads();
    sel[bb * NT + tid] = si;
    rw[bb * NT + tid] = e / bsum;
}

// ---------------------------------------------------------------------------
// Gather: xf[b,j,:] = x[b, sel[b,j], :]   (float4)
// ---------------------------------------------------------------------------
__global__ __launch_bounds__(256) void gather_k(const float* __restrict__ x,
                                                const int* __restrict__ sel,
                                                float* __restrict__ xf) {
    int gid = blockIdx.x * 256 + threadIdx.x;
    int col = gid & (ND / 4 - 1);
    int row = gid >> 9;
    int bb = row >> 10;
    int s = sel[row];
    ((float4*)xf)[gid] = ((const float4*)x)[((long long)bb * NS + s) * (ND / 4) + col];
}

// ---------------------------------------------------------------------------
// RMSNorm row kernel: out = bf16(x * rsqrt(mean(x^2)+eps) * g)
// ---------------------------------------------------------------------------
__global__ __launch_bounds__(256) void rmsnorm_k(const float* __restrict__ x,
                                                 const float* __restrict__ g,
                                                 bf16* __restrict__ out) {
    __shared__ float r4[4];
    __shared__ float scl;
    long long row = blockIdx.x;
    const float4* xr = (const float4*)(x + row * ND);
    int i0 = threadIdx.x, i1 = threadIdx.x + 256;
    float4 a = xr[i0], b = xr[i1];
    float ss = a.x * a.x + a.y * a.y + a.z * a.z + a.w * a.w +
               b.x * b.x + b.y * b.y + b.z * b.z + b.w * b.w;
    ss = wave_sum(ss);
    if ((threadIdx.x & 63) == 0) r4[threadIdx.x >> 6] = ss;
    __syncthreads();
    if (threadIdx.x == 0)
        scl = rsqrtf((r4[0] + r4[1] + r4[2] + r4[3]) * (1.0f / ND) + 1e-6f);
    __syncthreads();
    float s = scl;
    const float4* g4 = (const float4*)g;
    float4 ga = g4[i0], gb = g4[i1];
    bf16x4 o0, o1;
    o0[0] = (bf16)(a.x * s * ga.x); o0[1] = (bf16)(a.y * s * ga.y);
    o0[2] = (bf16)(a.z * s * ga.z); o0[3] = (bf16)(a.w * s * ga.w);
    o1[0] = (bf16)(b.x * s * gb.x); o1[1] = (bf16)(b.y * s * gb.y);
    o1[2] = (bf16)(b.z * s * gb.z); o1[3] = (bf16)(b.w * s * gb.w);
    *(bf16x4*)(out + row * ND + i0 * 4) = o0;
    *(bf16x4*)(out + row * ND + i1 * 4) = o1;
}

// ---------------------------------------------------------------------------
// Transpose + fp32->bf16: out[c][r] = in[r][c]; in is R x C. dims %32 == 0.
// ---------------------------------------------------------------------------
__global__ __launch_bounds__(256) void transpose_to_bf16(const float* __restrict__ in,
                                                         bf16* __restrict__ out,
                                                         int R, int C) {
    __shared__ float tile[32][33];
    int bx = blockIdx.x * 32;   // col
    int by = blockIdx.y * 32;   // row
    int tx = threadIdx.x & 31;
    int ty = threadIdx.x >> 5;   // 0..7
#pragma unroll
    for (int i = 0; i < 4; i++)
        tile[ty + 8 * i][tx] = in[(long long)(by + ty + 8 * i) * C + bx + tx];
    __syncthreads();
#pragma unroll
    for (int i = 0; i < 4; i++)
        out[(long long)(bx + ty + 8 * i) * R + by + tx] = (bf16)tile[tx][ty + 8 * i];
}

// ---------------------------------------------------------------------------
// RoPE + layout shuffle (reads fused QKV buffer, row stride 3*ND)
// ---------------------------------------------------------------------------
__global__ __launch_bounds__(256) void rope_k(const bf16* __restrict__ QKV,
                                              const float* __restrict__ fr,
                                              bf16* __restrict__ Q,
                                              bf16* __restrict__ K,
                                              bf16* __restrict__ Vt) {
    int gid = blockIdx.x * 256 + threadIdx.x;
    int hd = gid & 63;
    int h = (gid >> 6) & 15;
    int t = (gid >> 10) & (NT - 1);
    int bb = gid >> 20;
    float c = fr[t * 128 + hd * 2 + 0];
    float s = fr[t * 128 + hd * 2 + 1];
    long long base = ((long long)bb * NT + t) * (3 * ND) + h * NHD;
    float q1 = (float)QKV[base + hd],      q2 = (float)QKV[base + hd + 64];
    float k1 = (float)QKV[base + ND + hd], k2 = (float)QKV[base + ND + hd + 64];
    long long ob = (((long long)(bb * NH + h)) * NT + t) * NHD;
    Q[ob + hd]      = (bf16)(q1 * c - q2 * s);
    Q[ob + hd + 64] = (bf16)(q1 * s + q2 * c);
    K[ob + hd]      = (bf16)(k1 * c - k2 * s);
    K[ob + hd + 64] = (bf16)(k1 * s + k2 * c);
    long long vb = ((long long)(bb * NH + h)) * NHD * NT + t;
    Vt[vb + (long long)hd * NT]        = QKV[base + 2 * ND + hd];
    Vt[vb + (long long)(hd + 64) * NT] = QKV[base + 2 * ND + hd + 64];
}

// ---------------------------------------------------------------------------
__global__ __launch_bounds__(256) void copy_k(const float4* __restrict__ in,
                                              float4* __restrict__ out, long long n) {
    for (long long i = (long long)blockIdx.x * 256 + threadIdx.x; i < n;
         i += (long long)gridDim.x * 256)
        out[i] = in[i];
}

// ---------------------------------------------------------------------------
// Fused flash attention (non-causal, mask==0, S=1024, D=128).
//   Grid: (S/128, NB*NH). Block: 256 thr = 4 waves; wave w owns Q rows
//   [q0+32w, q0+32w+32). Q in registers; per 64-key chunk: K(64x128) and
//   Vt(128x64) staged in LDS (double-buffered, global_load_lds w=16,
//   both-sides XOR swizzle); QK^T -> online softmax (in-lane over 4 col
//   groups + shfl_xor over 16 lanes) -> P to wave-private LDS (swizzled)
//   -> PV accumulate O in fp32. Epilogue: O/l -> Obuf bf16.
//   Fragment conventions (verified m97/gemm256): A/B frag: lane&15 =
//   row/col, (lane>>4)*8+j = k; C frag: col=lane&15, row=lq*4+r.
// ---------------------------------------------------------------------------
__global__ __launch_bounds__(256, 2) void flash_k(
    const bf16* __restrict__ Qr,   // [(b*16+h)][t][128]
    const bf16* __restrict__ Kr,   // [(b*16+h)][t][128]
    const bf16* __restrict__ Vt,   // [(b*16+h)][d][1024]
    bf16* __restrict__ O) {        // [b*NT+t][ND], col h*128+d
    __shared__ char lds[81920];    // K: 2x16K @0, V: 2x16K @32768, P: 4x4K @65536

    const int tid = threadIdx.x;
    const int lane = tid & 63;
    const int w = tid >> 6;
    const int lm = lane & 15, lq = lane >> 4;
    const int lm7 = lm & 7;

    const int bh = blockIdx.y;
    const int q0 = blockIdx.x * 128;
    const bf16* Qb = Qr + (size_t)bh * NT * NHD;
    const bf16* Kb = Kr + (size_t)bh * NT * NHD;
    const bf16* Vb = Vt + (size_t)bh * NHD * NT;

    // ---- staging coords (block-wide) ----
    // K chunk: 64 rows x 256 B (16 chunks of 16B); V chunk: 128 rows x 128 B.
    const int krow = tid >> 4;              // + i*16, i<4
    const int kc_s = (tid & 15);
    const int vrow = tid >> 3;              // + i*32, i<4
    const int vc_s = (tid & 7);

    // ---- Q fragments (permanent) ----
    bf16x8 q[2][4];
#pragma unroll
    for (int mi = 0; mi < 2; mi++)
#pragma unroll
        for (int ks = 0; ks < 4; ks++)
            q[mi][ks] = *(const bf16x8*)(Qb + (size_t)(q0 + w * 32 + mi * 16 + lm) * NHD
                                         + lq * 8 + ks * 32);

    f32x4 o0[8], o1[8];
#pragma unroll
    for (int i = 0; i < 8; i++) {
        f32x4 zz = {0.f, 0.f, 0.f, 0.f};
        o0[i] = zz; o1[i] = zz;
    }
    float m0[4], m1[4], l0[4], l1[4];
#pragma unroll
    for (int r = 0; r < 4; r++) {
        m0[r] = -3.0e38f; m1[r] = -3.0e38f; l0[r] = 0.f; l1[r] = 0.f;
    }

    char* Pb = lds + 65536 + w * 4096;
    const float scal = 0.08838834764831845f;   // 1/sqrt(128)

    // ---- stage chunk 0 ----
#pragma unroll
    for (int i = 0; i < 4; i++) {
        int row = i * 16 + krow;
        __builtin_amdgcn_global_load_lds(
            (gptr_t)(Kb + (size_t)row * NHD + (kc_s ^ (row & 7)) * 8),
            (lptr_t)(lds + i * 4096 + tid * 16), 16, 0, 0);
    }
#pragma unroll
    for (int i = 0; i < 4; i++) {
        int row = i * 32 + vrow;
        __builtin_amdgcn_global_load_lds(
            (gptr_t)(Vb + (size_t)row * NT + (vc_s ^ (row & 7)) * 8),
            (lptr_t)(lds + 32768 + i * 4096 + tid * 16), 16, 0, 0);
    }
    __syncthreads();

    for (int c = 0; c < 16; ++c) {
        char* Kl = lds + (c & 1) * 16384;
        char* Vl = lds + 32768 + (c & 1) * 16384;

        // stage chunk c+1 into the other buffer (read-safe: barrier at end of
        // chunk c-1 released it)
        if (c < 15) {
            const int key1 = (c + 1) * 64;
            char* Kd = lds + ((c + 1) & 1) * 16384;
            char* Vd = lds + 32768 + ((c + 1) & 1) * 16384;
#pragma unroll
            for (int i = 0; i < 4; i++) {
                int row = i * 16 + krow;
                __builtin_amdgcn_global_load_lds(
                    (gptr_t)(Kb + (size_t)(key1 + row) * NHD + (kc_s ^ (row & 7)) * 8),
                    (lptr_t)(Kd + i * 4096 + tid * 16), 16, 0, 0);
            }
#pragma unroll
            for (int i = 0; i < 4; i++) {
                int row = i * 32 + vrow;
                __builtin_amdgcn_global_load_lds(
                    (gptr_t)(Vb + (size_t)row * NT + key1 + (vc_s ^ (row & 7)) * 8),
                    (lptr_t)(Vd + i * 4096 + tid * 16), 16, 0, 0);
            }
        }

        // ---- QK^T: S[32 q][64 key] per wave ----
        f32x4 s0[4], s1[4];
#pragma unroll
        for (int ni = 0; ni < 4; ni++) {
            f32x4 zz = {0.f, 0.f, 0.f, 0.f};
            s0[ni] = zz; s1[ni] = zz;
        }
#pragma unroll
        for (int ni = 0; ni < 4; ni++) {
#pragma unroll
            for (int ks = 0; ks < 4; ks++) {
                bf16x8 kf = *(const bf16x8*)(Kl + (lm + 16 * ni) * 256
                                             + (((lq + 4 * ks) ^ lm7) << 4));
                s0[ni] = __builtin_amdgcn_mfma_f32_16x16x32_bf16(q[0][ks], kf, s0[ni], 0, 0, 0);
                s1[ni] = __builtin_amdgcn_mfma_f32_16x16x32_bf16(q[1][ks], kf, s1[ni], 0, 0, 0);
            }
        }

        // ---- online softmax (rows: mi*16 + lq*4 + r; cols: lm + 16*ni) ----
        float sc0[4], sc1[4];
#pragma unroll
        for (int r = 0; r < 4; r++) {
            float a0 = fmaxf(fmaxf(s0[0][r], s0[1][r]), fmaxf(s0[2][r], s0[3][r])) * scal;
            float a1 = fmaxf(fmaxf(s1[0][r], s1[1][r]), fmaxf(s1[2][r], s1[3][r])) * scal;
#pragma unroll
            for (int o = 1; o < 16; o <<= 1) {
                a0 = fmaxf(a0, __shfl_xor(a0, o));
                a1 = fmaxf(a1, __shfl_xor(a1, o));
            }
            float mn0 = fmaxf(m0[r], a0);
            float mn1 = fmaxf(m1[r], a1);
            sc0[r] = __expf(m0[r] - mn0);
            sc1[r] = __expf(m1[r] - mn1);
            m0[r] = mn0; m1[r] = mn1;

            float rs0 = 0.f, rs1 = 0.f;
#pragma unroll
            for (int ni = 0; ni < 4; ni++) {
                float p0 = __expf(s0[ni][r] * scal - mn0);
                float p1 = __expf(s1[ni][r] * scal - mn1);
                s0[ni][r] = p0; s1[ni][r] = p1;
                rs0 += p0; rs1 += p1;
            }
#pragma unroll
            for (int o = 1; o < 16; o <<= 1) {
                rs0 += __shfl_xor(rs0, o);
                rs1 += __shfl_xor(rs1, o);
            }
            l0[r] = l0[r] * sc0[r] + rs0;
            l1[r] = l1[r] * sc1[r] + rs1;
        }
        // rescale O
#pragma unroll
        for (int ni = 0; ni < 8; ni++)
#pragma unroll
            for (int r = 0; r < 4; r++) {
                o0[ni][r] *= sc0[r];
                o1[ni][r] *= sc1[r];
            }

        // ---- P -> wave-private LDS (bf16, swizzled rows of 128 B) ----
#pragma unroll
        for (int ni = 0; ni < 4; ni++)
#pragma unroll
            for (int r = 0; r < 4; r++) {
                int q_l0 = lq * 4 + r;              // mi=0
                int q_l1 = 16 + q_l0;               // mi=1
                int cw = (lm >> 3) + 2 * ni;        // key/8
                *(bf16*)(Pb + q_l0 * 128 + ((cw ^ (q_l0 & 7)) << 4) + (lm7 << 1)) =
                    (bf16)s0[ni][r];
                *(bf16*)(Pb + q_l1 * 128 + ((cw ^ (q_l1 & 7)) << 4) + (lm7 << 1)) =
                    (bf16)s1[ni][r];
            }
        asm volatile("s_waitcnt lgkmcnt(0)" ::: "memory");
        __builtin_amdgcn_sched_barrier(0);

        // ---- PV: O[32 q][128 d] += P(32x64) . V(64x128) ----
#pragma unroll
        for (int ks = 0; ks < 2; ks++) {
            bf16x8 pa0 = *(const bf16x8*)(Pb + lm * 128 + (((lq + 4 * ks) ^ lm7) << 4));
            bf16x8 pa1 = *(const bf16x8*)(Pb + (lm + 16) * 128 + (((lq + 4 * ks) ^ lm7) << 4));
#pragma unroll
            for (int ni = 0; ni < 8; ni++) {
                bf16x8 vf = *(const bf16x8*)(Vl + (lm + 16 * ni) * 128
                                             + (((lq + 4 * ks) ^ lm7) << 4));
                o0[ni] = __builtin_amdgcn_mfma_f32_16x16x32_bf16(pa0, vf, o0[ni], 0, 0, 0);
                o1[ni] = __builtin_amdgcn_mfma_f32_16x16x32_bf16(pa1, vf, o1[ni], 0, 0, 0);
            }
        }

        __syncthreads();   // drains vmcnt (chunk c+1 staged) + releases bufs
    }

    // ---- epilogue: O / l -> Obuf ----
    const int bb = bh >> 4, h = bh & 15;
    float rl0[4], rl1[4];
#pragma unroll
    for (int r = 0; r < 4; r++) { rl0[r] = 1.f / l0[r]; rl1[r] = 1.f / l1[r]; }
#pragma unroll
    for (int ni = 0; ni < 8; ni++) {
#pragma unroll
        for (int r = 0; r < 4; r++) {
            int col = h * 128 + lm + 16 * ni;
            long long r0 = (long long)bb * NT + q0 + w * 32 + lq * 4 + r;
            O[(r0) * ND + col]      = (bf16)(o0[ni][r] * rl0[r]);
            O[(r0 + 16) * ND + col] = (bf16)(o1[ni][r] * rl1[r]);
        }
    }
}

// ---------------------------------------------------------------------------
// 256-wide 8-phase pipelined GEMM (T2+T3+T4+T5), L2-aware 2D XCD mapping.
//   MODE 0: C bf16 = alpha*acc (256-N tile)
//   MODE 2: C fp32 atomic += acc (256-N, split-K via blockIdx.z)
//   MODE 5: out[(b*NS+sel[m])*ND+n] atomic += rw[m]*(acc+(z==0)*res) (256-N)
//   MODE 6: dual-B (Bt=w1_t, Bt2=w3_t), 128-N tile per matrix;
//           C bf16 = silu(acc1)*acc3  (fused FFN up-projection)
// ---------------------------------------------------------------------------
#define G256_BAR() do { __builtin_amdgcn_sched_barrier(0); \
    __builtin_amdgcn_s_barrier(); __builtin_amdgcn_sched_barrier(0); } while (0)
#define G256_LGKM0() do { asm volatile("s_waitcnt lgkmcnt(0)" ::: "memory"); \
    __builtin_amdgcn_sched_barrier(0); } while (0)
#define G256_VMC(n) do { asm volatile("s_waitcnt vmcnt(" #n ")" ::: "memory"); \
    __builtin_amdgcn_sched_barrier(0); } while (0)

#define STAGE_A(c, h, t) do { \
    char* _l = sm + (c) * 65536 + (h) * 16384 + sdst; \
    long long _ko = (long long)(t) * 64; \
    __builtin_amdgcn_global_load_lds((gptr_t)(gA + (2 * (h)) * stA + _ko), \
                                     (lptr_t)_l, 16, 0, 0); \
    __builtin_amdgcn_global_load_lds((gptr_t)(gA + (2 * (h) + 1) * stA + _ko), \
                                     (lptr_t)(_l + 8192), 16, 0, 0); \
} while (0)
#define STAGE_B(c, h, t) do { \
    char* _l = sm + (c) * 65536 + 32768 + (h) * 16384 + sdst; \
    long long _ko = (long long)(t) * 64; \
    const bf16* _g = (h) ? gBhi : gBlo; \
    __builtin_amdgcn_global_load_lds((gptr_t)(_g + _ko), \
                                     (lptr_t)_l, 16, 0, 0); \
    __builtin_amdgcn_global_load_lds((gptr_t)(_g + stB + _ko), \
                                     (lptr_t)(_l + 8192), 16, 0, 0); \
} while (0)

#define LDA_HALF(c, lo) do { \
    char* _b = sm + (c) * 65536; \
    _Pragma("unroll") \
    for (int _mi = 0; _mi < 4; _mi++) { \
        a[(lo) + _mi][0] = *(const bf16x8*)(_b + aoff + ((lo) + _mi) * 2048); \
        a[(lo) + _mi][1] = *(const bf16x8*)(_b + (aoff ^ 64) + ((lo) + _mi) * 2048); \
    } \
} while (0)
#define LDB_HALF(c, lo) do { \
    char* _b = sm + (c) * 65536 + 32768; \
    _Pragma("unroll") \
    for (int _ni = 0; _ni < 2; _ni++) { \
        int _ix = (lo) + _ni; \
        int _o = boff + (_ix & 1) * 2048 + (_ix >> 1) * bStep2; \
        b[_ix][0] = *(const bf16x8*)(_b + _o); \
        b[_ix][1] = *(const bf16x8*)(_b + (_o ^ 64)); \
    } \
} while (0)

#define MFMA_Q(mlo, nlo) do { \
    __builtin_amdgcn_s_setprio(1); \
    _Pragma("unroll") \
    for (int _ks = 0; _ks < 2; _ks++) \
    _Pragma("unroll") \
    for (int _mi = 0; _mi < 4; _mi++) \
    _Pragma("unroll") \
    for (int _ni = 0; _ni < 2; _ni++) \
        acc[(mlo) + _mi][(nlo) + _ni] = __builtin_amdgcn_mfma_f32_16x16x32_bf16( \
            a[(mlo) + _mi][_ks], b[(nlo) + _ni][_ks], acc[(mlo) + _mi][(nlo) + _ni], \
            0, 0, 0); \
    __builtin_amdgcn_s_setprio(0); \
} while (0)

template <int MODE>
__global__ __launch_bounds__(512, 2) void gemm256(
    const bf16* __restrict__ A, int lda,
    const bf16* __restrict__ Bt, int ldb,
    void* __restrict__ Cv, int ldc,
    int K, float alpha,
    const bf16* __restrict__ Bt2,
    const float* __restrict__ res, const int* __restrict__ selp,
    const float* __restrict__ rwp, float* __restrict__ outp) {
    __shared__ char smem[131072];   // buf c: A @ c*65536, B @ c*65536+32768

    constexpr bool DUALB = (MODE == 6);
    constexpr int bStep2 = DUALB ? 16384 : 4096;   // byte offset ni=2 vs ni=0

    const int tid = threadIdx.x;
    const int lane = tid & 63;
    const int wid = tid >> 6;
    const int wm = wid >> 2, wn = wid & 3;     // 2 x 4 waves
    const int lm = lane & 15, lq = lane >> 4;

    // 2D XCD mapping: xcd quadrant (2 in M x 4 in N), 8 x (nx/4) rect inside,
    // M-first so concurrent blocks share B panels. Requires ny==16, nx%4==0.
    const int nx = gridDim.x;
    const int orig = blockIdx.y * nx + blockIdx.x;
    const int xcd = orig & 7;
    const int r_ = orig >> 3;                  // [0, 2*nx)
    const int mi_ = r_ & 7, ni_ = r_ >> 3;     // 8 x (nx/4)
    const int nTile = DUALB ? 128 : 256;
    const int m0 = ((xcd >> 2) * 8 + mi_) * 256;
    const int n0 = ((xcd & 3) * (nx >> 2) + ni_) * nTile;
    const long long kz = (long long)blockIdx.z * K;

    // staging: thread stages 16B chunk (row = chunk*64 + tid>>3, kchunk = tid&7);
    // LDS linear, global source pre-swizzled: kc_src = (tid&7) ^ (row&7)
    const int srow = tid >> 3;                 // [0,64)
    const int skc = ((tid & 7) ^ (srow & 7)) * 8;
    const bf16* gA = A + (long long)(m0 + srow) * lda + kz + skc;
    const bf16* gBlo = Bt + (long long)(n0 + srow) * ldb + kz + skc;
    const bf16* gBhi = DUALB
        ? Bt2 + (long long)(n0 + srow) * ldb + kz + skc
        : gBlo + (long long)128 * ldb;
    const long long stA = (long long)64 * lda;
    const long long stB = (long long)64 * ldb;

    char* sm = (char*)smem;
    const int sdst = tid * 16;

    // frag read offsets: row*128 + ((ks*4+lq) ^ (lm&7))*16 ; ks=1 is ^64
    const int aoff = (wm * 128 + lm) * 128 + ((lq ^ (lm & 7)) << 4);
    const int boff = ((DUALB ? wn * 32 : wn * 64) + lm) * 128 + ((lq ^ (lm & 7)) << 4);

    f32x4 acc[8][4];
#pragma unroll
    for (int i = 0; i < 8; i++)
#pragma unroll
        for (int j = 0; j < 4; j++) {
            f32x4 zz = {0.f, 0.f, 0.f, 0.f};
            acc[i][j] = zz;
        }
    bf16x8 a[8][2], b[4][2];

    const int NTk = K >> 6;   // even, >= 16 for all launches here

    // prologue: A(0) full, B(0) full, A(1) full = 12 loads; wait tile0 (8 oldest)
    STAGE_A(0, 0, 0); STAGE_A(0, 1, 0);
    STAGE_B(0, 0, 0); STAGE_B(0, 1, 0);
    STAGE_A(1, 0, 1); STAGE_A(1, 1, 1);
    G256_VMC(4);
    G256_BAR();

    for (int t0 = 0; t0 < NTk; t0 += 2) {
        const int t1 = t0 + 1, t2 = t0 + 2, t3 = t0 + 3;
        const bool more = (t2 < NTk);

        // ---- K-tile t0 (buf 0) ----
        LDA_HALF(0, 0); LDB_HALF(0, 0);
        STAGE_B(1, 0, t1);
        G256_BAR(); G256_LGKM0(); MFMA_Q(0, 0); G256_BAR();
        LDA_HALF(0, 4);
        STAGE_B(1, 1, t1);
        G256_BAR(); G256_LGKM0(); MFMA_Q(4, 0); G256_BAR();
        LDB_HALF(0, 2);
        if (more) STAGE_A(0, 0, t2);
        G256_BAR(); G256_LGKM0(); MFMA_Q(0, 2); G256_BAR();
        if (more) STAGE_A(0, 1, t2);
        G256_BAR(); G256_LGKM0(); MFMA_Q(4, 2);
        if (more) { G256_VMC(4); } else { G256_VMC(0); }
        G256_BAR();

        // ---- K-tile t1 (buf 1) ----
        LDA_HALF(1, 0); LDB_HALF(1, 0);
        if (more) STAGE_B(0, 0, t2);
        G256_BAR(); G256_LGKM0(); MFMA_Q(0, 0); G256_BAR();
        LDA_HALF(1, 4);
        if (more) STAGE_B(0, 1, t2);
        G256_BAR(); G256_LGKM0(); MFMA_Q(4, 0); G256_BAR();
        LDB_HALF(1, 2);
        if (more) STAGE_A(1, 0, t3);
        G256_BAR(); G256_LGKM0(); MFMA_Q(0, 2); G256_BAR();
        if (more) STAGE_A(1, 1, t3);
        G256_BAR(); G256_LGKM0(); MFMA_Q(4, 2);
        if (more) { G256_VMC(4); } else { G256_VMC(0); }
        G256_BAR();
    }

    if constexpr (MODE == 6) {
        bf16* C = (bf16*)Cv;
#pragma unroll
        for (int mi = 0; mi < 8; mi++) {
#pragma unroll
            for (int ni = 0; ni < 2; ni++) {
                const int row = m0 + wm * 128 + mi * 16 + lq * 4;
                const int col = n0 + wn * 32 + ni * 16 + lm;
#pragma unroll
                for (int r = 0; r < 4; r++) {
                    float v1 = acc[mi][ni][r];
                    float v3 = acc[mi][ni + 2][r];
                    C[(long long)(row + r) * ldc + col] =
                        (bf16)((v1 / (1.f + __expf(-v1))) * v3);
                }
            }
        }
    } else {
#pragma unroll
        for (int mi = 0; mi < 8; mi++) {
#pragma unroll
            for (int ni = 0; ni < 4; ni++) {
                const int row = m0 + wm * 128 + mi * 16 + lq * 4;
                const int col = n0 + wn * 64 + ni * 16 + lm;
#pragma unroll
                for (int r = 0; r < 4; r++) {
                    float v = alpha * acc[mi][ni][r];
                    long long rr = row + r;
                    if constexpr (MODE == 0) {
                        bf16* C = (bf16*)Cv;
                        C[rr * ldc + col] = (bf16)v;
                    } else if constexpr (MODE == 2) {
                        float* C = (float*)Cv;
                        unsafeAtomicAdd(&C[rr * ldc + col], v);
                    } else {   // MODE 5
                        int bb2 = (int)(rr >> 10);
                        int s = selp[rr];
                        float add = rwp[rr] *
                            (v + (blockIdx.z == 0 ? res[rr * (long long)ND + col] : 0.f));
                        unsafeAtomicAdd(outp + ((long long)bb2 * NS + s) * ND + col, add);
                    }
                }
            }
        }
    }
}

// ---------------------------------------------------------------------------
extern "C" void kernel_launch(void* const* d_in, const int* in_sizes, int n_in,
                              void* d_out, int out_size, void* d_ws, size_t ws_size,
                              hipStream_t stream) {
    const float* x  = (const float*)d_in[0];
    const float* fr = (const float*)d_in[2];
    const float* wr = (const float*)d_in[3];
    const float* g1 = (const float*)d_in[4];
    const float* wq = (const float*)d_in[5];
    const float* wk = (const float*)d_in[6];
    const float* wv = (const float*)d_in[7];
    const float* wo = (const float*)d_in[8];
    const float* g2 = (const float*)d_in[9];
    const float* w1 = (const float*)d_in[10];
    const float* w3 = (const float*)d_in[11];
    const float* w2 = (const float*)d_in[12];
    float* out = (float*)d_out;

    char* ws = (char*)d_ws;
    size_t off = 0;
    auto take = [&](size_t bytes) -> char* {
        char* p = ws + off;
        off += (bytes + 255) & ~(size_t)255;
        return p;
    };
    int*   sel    = (int*)take((size_t)NB * NT * 4);
    float* rw     = (float*)take((size_t)NB * NT * 4);
    float* logits = (float*)take((size_t)NB * NS * 4);
    float* xf     = (float*)take((size_t)NB * NT * ND * 4);
    bf16*  hbuf   = (bf16*)take((size_t)NB * NT * ND * 2);
    bf16*  wqkv_t = (bf16*)take((size_t)3 * ND * ND * 2);
    bf16*  wo_t   = (bf16*)take((size_t)ND * ND * 2);
    bf16*  Obuf   = (bf16*)take((size_t)NB * NT * ND * 2);
    char* xr = ws + off;
    // attention-phase overlay
    bf16* QKV = (bf16*)xr;                               // [4096][6144]
    bf16* Qr  = QKV + (size_t)NB * NT * 3 * ND;
    bf16* Kr  = Qr + (size_t)NB * NT * ND;
    bf16* Vt  = Kr + (size_t)NB * NT * ND;
    // FFN-phase overlay (attention data dead by then)
    bf16* w1_t  = (bf16*)xr;
    bf16* w3_t  = w1_t + (size_t)ND * NF;
    bf16* w2_t  = w3_t + (size_t)ND * NF;
    bf16* inter = w2_t + (size_t)ND * NF;

    router_k<<<NB * NS, 256, 0, stream>>>(x, wr, logits);
    topk_k<<<NB, 1024, 0, stream>>>(logits, sel, rw);
    gather_k<<<(NB * NT * ND / 4) / 256, 256, 0, stream>>>(x, sel, xf);
    rmsnorm_k<<<NB * NT, 256, 0, stream>>>(xf, g1, hbuf);

    dim3 tg(ND / 32, ND / 32);
    transpose_to_bf16<<<tg, 256, 0, stream>>>(wq, wqkv_t, ND, ND);
    transpose_to_bf16<<<tg, 256, 0, stream>>>(wk, wqkv_t + (size_t)ND * ND, ND, ND);
    transpose_to_bf16<<<tg, 256, 0, stream>>>(wv, wqkv_t + (size_t)2 * ND * ND, ND, ND);
    transpose_to_bf16<<<tg, 256, 0, stream>>>(wo, wo_t, ND, ND);

    // fused QKV: [4096 x 2048] x [6144 x 2048]^T -> [4096][6144]
    gemm256<0><<<dim3(3 * ND / 256, NB * NT / 256, 1), 512, 0, stream>>>(
        hbuf, ND, wqkv_t, ND, QKV, 3 * ND, ND, 1.0f,
        nullptr, nullptr, nullptr, nullptr, nullptr);

    rope_k<<<(NB * NT * NH * 64) / 256, 256, 0, stream>>>(QKV, fr, Qr, Kr, Vt);

    // fused flash attention: replaces QK^T gemm + softmax + PV gemm
    flash_k<<<dim3(NT / 128, NB * NH), 256, 0, stream>>>(Qr, Kr, Vt, Obuf);

    // WO: split-K x2 (K=1024 each), atomic += into xf residual
    gemm256<2><<<dim3(ND / 256, NB * NT / 256, 2), 512, 0, stream>>>(
        Obuf, ND, wo_t, ND, xf, ND, ND / 2, 1.0f,
        nullptr, nullptr, nullptr, nullptr, nullptr);

    rmsnorm_k<<<NB * NT, 256, 0, stream>>>(xf, g2, hbuf);

    transpose_to_bf16<<<dim3(NF / 32, ND / 32), 256, 0, stream>>>(w1, w1_t, ND, NF);
    transpose_to_bf16<<<dim3(NF / 32, ND / 32), 256, 0, stream>>>(w3, w3_t, ND, NF);
    transpose_to_bf16<<<dim3(ND / 32, NF / 32), 256, 0, stream>>>(w2, w2_t, NF, ND);

    // fused FFN up: inter = silu(h.w1) * (h.w3), one dual-B dispatch
    gemm256<6><<<dim3(NF / 128, NB * NT / 256, 1), 512, 0, stream>>>(
        hbuf, ND, w1_t, ND, inter, NF, ND, 1.0f,
        w3_t, nullptr, nullptr, nullptr, nullptr);

    copy_k<<<8192, 256, 0, stream>>>((const float4*)x, (float4*)out,
                                     (long long)NB * NS * ND / 4);
    // w2 + scatter-add: split-K x2 (K=4096 each), res added on z==0 only
    gemm256<5><<<dim3(ND / 256, NB * NT / 256, 2), 512, 0, stream>>>(
        inter, NF, w2_t, NF, nullptr, ND, NF / 2, 1.0f,
        nullptr, xf, sel, rw, out);
}

// Round 6
// 1299.253 us; speedup vs baseline: 1.1919x; 1.0179x over previous
//
#include <hip/hip_runtime.h>
#include <cstdint>
#include <cstddef>

#define NB 4
#define NS 4096
#define ND 2048
#define NH 16
#define NHD 128
#define NT 1024
#define NF 8192

typedef __bf16 bf16;
typedef __bf16 bf16x8 __attribute__((ext_vector_type(8)));
typedef __bf16 bf16x4 __attribute__((ext_vector_type(4)));
typedef float  f32x4  __attribute__((ext_vector_type(4)));

typedef const __attribute__((address_space(1))) void* gptr_t;
typedef __attribute__((address_space(3))) void* lptr_t;

__device__ __forceinline__ float wave_sum(float v) {
#pragma unroll
    for (int off = 32; off > 0; off >>= 1) v += __shfl_xor(v, off);
    return v;
}
__device__ __forceinline__ float wave_max(float v) {
#pragma unroll
    for (int off = 32; off > 0; off >>= 1) v = fmaxf(v, __shfl_xor(v, off));
    return v;
}

// ---------------------------------------------------------------------------
// Router: logits[row] = dot(x[row,:], w_router)   (row = b*NS+s)
// ---------------------------------------------------------------------------
__global__ __launch_bounds__(256) void router_k(const float* __restrict__ x,
                                                const float* __restrict__ wr,
                                                float* __restrict__ logits) {
    __shared__ float r4[4];
    long long row = blockIdx.x;
    const float4* xr = (const float4*)(x + row * ND);
    const float4* w4 = (const float4*)wr;
    float p = 0.f;
    for (int i = threadIdx.x; i < ND / 4; i += 256) {
        float4 a = xr[i], b = w4[i];
        p += a.x * b.x + a.y * b.y + a.z * b.z + a.w * b.w;
    }
    p = wave_sum(p);
    if ((threadIdx.x & 63) == 0) r4[threadIdx.x >> 6] = p;
    __syncthreads();
    if (threadIdx.x == 0) logits[row] = r4[0] + r4[1] + r4[2] + r4[3];
}

// ---------------------------------------------------------------------------
// Top-K (exact, matches jax.lax.top_k tie-break) + index sort + router softmax.
// ---------------------------------------------------------------------------
__global__ __launch_bounds__(1024) void topk_k(const float* __restrict__ logits,
                                               int* __restrict__ sel,
                                               float* __restrict__ rw) {
    __shared__ unsigned long long keys[NS];   // 32 KB
    __shared__ float r16[16];
    __shared__ float bmax, bsum;
    const int bb = blockIdx.x;
    const int tid = threadIdx.x;
    const float* lg = logits + (long long)bb * NS;

    for (int i = tid; i < NS; i += 1024) {
        unsigned u = __float_as_uint(lg[i]);
        u = (u & 0x80000000u) ? ~u : (u | 0x80000000u);   // order-preserving map
        keys[i] = ((unsigned long long)u << 32) | (unsigned)(NS - 1 - i);
    }
    __syncthreads();
    for (int k = 2; k <= NS; k <<= 1) {
        for (int j = k >> 1; j > 0; j >>= 1) {
            for (int i = tid; i < NS; i += 1024) {
                int ixj = i ^ j;
                if (ixj > i) {
                    unsigned long long a = keys[i], c = keys[ixj];
                    bool up = ((i & k) == 0);
                    if (up ? (a < c) : (a > c)) { keys[i] = c; keys[ixj] = a; }
                }
            }
            __syncthreads();
        }
    }
    unsigned long long a0 = keys[tid];
    __syncthreads();
    {
        unsigned idx_ = NS - 1 - (unsigned)(a0 & 0xFFFFFFFFu);
        unsigned uval = (unsigned)(a0 >> 32);
        keys[tid] = ((unsigned long long)idx_ << 32) | uval;
    }
    __syncthreads();
    for (int k = 2; k <= NT; k <<= 1) {
        for (int j = k >> 1; j > 0; j >>= 1) {
            int i = tid, ixj = i ^ j;
            if (i < NT && ixj > i) {
                unsigned long long a = keys[i], c = keys[ixj];
                bool up = ((i & k) == 0);
                if (up ? (a > c) : (a < c)) { keys[i] = c; keys[ixj] = a; }
            }
            __syncthreads();
        }
    }
    unsigned long long kk = keys[tid];
    int si = (int)(kk >> 32);
    unsigned u = (unsigned)(kk & 0xFFFFFFFFu);
    u = (u & 0x80000000u) ? (u ^ 0x80000000u) : ~u;
    float val = __uint_as_float(u);

    const int wid = tid >> 6, lane = tid & 63;
    float mx = wave_max(val);
    if (lane == 0) r16[wid] = mx;
    __syncthreads();
    if (tid == 0) {
        float m = r16[0];
        for (int i = 1; i < 16; i++) m = fmaxf(m, r16[i]);
        bmax = m;
    }
    __syncthreads();
    float e = __expf(val - bmax);
    float s = wave_sum(e);
    if (lane == 0) r16[wid] = s;
    __syncthreads();
    if (tid == 0) {
        float t = 0.f;
        for (int i = 0; i < 16; i++) t += r16[i];
        bsum = t;
    }
    __syncthreads();
    sel[bb * NT + tid] = si;
    rw[bb * NT + tid] = e / bsum;
}

// ---------------------------------------------------------------------------
// Gather: xf[b,j,:] = x[b, sel[b,j], :]   (float4)
// ---------------------------------------------------------------------------
__global__ __launch_bounds__(256) void gather_k(const float* __restrict__ x,
                                                const int* __restrict__ sel,
                                                float* __restrict__ xf) {
    int gid = blockIdx.x * 256 + threadIdx.x;
    int col = gid & (ND / 4 - 1);
    int row = gid >> 9;
    int bb = row >> 10;
    int s = sel[row];
    ((float4*)xf)[gid] = ((const float4*)x)[((long long)bb * NS + s) * (ND / 4) + col];
}

// ---------------------------------------------------------------------------
// RMSNorm row kernel: out = bf16(x * rsqrt(mean(x^2)+eps) * g)
// ---------------------------------------------------------------------------
__global__ __launch_bounds__(256) void rmsnorm_k(const float* __restrict__ x,
                                                 const float* __restrict__ g,
                                                 bf16* __restrict__ out) {
    __shared__ float r4[4];
    __shared__ float scl;
    long long row = blockIdx.x;
    const float4* xr = (const float4*)(x + row * ND);
    int i0 = threadIdx.x, i1 = threadIdx.x + 256;
    float4 a = xr[i0], b = xr[i1];
    float ss = a.x * a.x + a.y * a.y + a.z * a.z + a.w * a.w +
               b.x * b.x + b.y * b.y + b.z * b.z + b.w * b.w;
    ss = wave_sum(ss);
    if ((threadIdx.x & 63) == 0) r4[threadIdx.x >> 6] = ss;
    __syncthreads();
    if (threadIdx.x == 0)
        scl = rsqrtf((r4[0] + r4[1] + r4[2] + r4[3]) * (1.0f / ND) + 1e-6f);
    __syncthreads();
    float s = scl;
    const float4* g4 = (const float4*)g;
    float4 ga = g4[i0], gb = g4[i1];
    bf16x4 o0, o1;
    o0[0] = (bf16)(a.x * s * ga.x); o0[1] = (bf16)(a.y * s * ga.y);
    o0[2] = (bf16)(a.z * s * ga.z); o0[3] = (bf16)(a.w * s * ga.w);
    o1[0] = (bf16)(b.x * s * gb.x); o1[1] = (bf16)(b.y * s * gb.y);
    o1[2] = (bf16)(b.z * s * gb.z); o1[3] = (bf16)(b.w * s * gb.w);
    *(bf16x4*)(out + row * ND + i0 * 4) = o0;
    *(bf16x4*)(out + row * ND + i1 * 4) = o1;
}

// ---------------------------------------------------------------------------
// Transpose + fp32->bf16: out[c][r] = in[r][c]; in is R x C. dims %32 == 0.
// ---------------------------------------------------------------------------
__global__ __launch_bounds__(256) void transpose_to_bf16(const float* __restrict__ in,
                                                         bf16* __restrict__ out,
                                                         int R, int C) {
    __shared__ float tile[32][33];
    int bx = blockIdx.x * 32;   // col
    int by = blockIdx.y * 32;   // row
    int tx = threadIdx.x & 31;
    int ty = threadIdx.x >> 5;   // 0..7
#pragma unroll
    for (int i = 0; i < 4; i++)
        tile[ty + 8 * i][tx] = in[(long long)(by + ty + 8 * i) * C + bx + tx];
    __syncthreads();
#pragma unroll
    for (int i = 0; i < 4; i++)
        out[(long long)(bx + ty + 8 * i) * R + by + tx] = (bf16)tile[tx][ty + 8 * i];
}

// ---------------------------------------------------------------------------
// RoPE for Q,K only (reads fused QKV buffer, row stride 3*ND). Coalesced.
// ---------------------------------------------------------------------------
__global__ __launch_bounds__(256) void rope_qk_k(const bf16* __restrict__ QKV,
                                                 const float* __restrict__ fr,
                                                 bf16* __restrict__ Q,
                                                 bf16* __restrict__ K) {
    int gid = blockIdx.x * 256 + threadIdx.x;
    int hd = gid & 63;
    int h = (gid >> 6) & 15;
    int t = (gid >> 10) & (NT - 1);
    int bb = gid >> 20;
    float c = fr[t * 128 + hd * 2 + 0];
    float s = fr[t * 128 + hd * 2 + 1];
    long long base = ((long long)bb * NT + t) * (3 * ND) + h * NHD;
    float q1 = (float)QKV[base + hd],      q2 = (float)QKV[base + hd + 64];
    float k1 = (float)QKV[base + ND + hd], k2 = (float)QKV[base + ND + hd + 64];
    long long ob = (((long long)(bb * NH + h)) * NT + t) * NHD;
    Q[ob + hd]      = (bf16)(q1 * c - q2 * s);
    Q[ob + hd + 64] = (bf16)(q1 * s + q2 * c);
    K[ob + hd]      = (bf16)(k1 * c - k2 * s);
    K[ob + hd + 64] = (bf16)(k1 * s + k2 * c);
}

// ---------------------------------------------------------------------------
// V transpose via LDS tile: Vt[(b*16+h)][d][t] = QKV[b*NT+t][2*ND + h*128 + d].
// Grid: (NT/64, NB*NH). Coalesced 256B reads; 64B-contiguous row writes.
// ---------------------------------------------------------------------------
__global__ __launch_bounds__(256) void vtr_k(const bf16* __restrict__ QKV,
                                             bf16* __restrict__ Vt) {
    __shared__ bf16 tile[64][136];   // padded: row stride 272B (16B-aligned, odd*16)
    const int tt = blockIdx.x * 64;
    const int bh = blockIdx.y;
    const int bb = bh >> 4, h = bh & 15;
    const int tid = threadIdx.x;

    const int lt = tid >> 4;            // 0..15
    const int ld = (tid & 15) * 8;      // d-octet
#pragma unroll
    for (int i = 0; i < 4; i++) {
        int t = i * 16 + lt;
        bf16x8 v = *(const bf16x8*)(QKV + ((size_t)(bb * NT) + tt + t) * (3 * ND)
                                    + 2 * ND + h * NHD + ld);
        *(bf16x8*)&tile[t][ld] = v;
    }
    __syncthreads();

    const int d = tid >> 1;             // 0..127
    const int j0 = (tid & 1) * 32;      // t-half
    bf16 tmp[32];
#pragma unroll
    for (int j = 0; j < 32; j++) tmp[j] = tile[j0 + j][d];
    bf16* dst = Vt + ((size_t)bh * NHD + d) * NT + tt + j0;
#pragma unroll
    for (int j = 0; j < 4; j++)
        *(bf16x8*)(dst + j * 8) = *(const bf16x8*)(tmp + j * 8);
}

// ---------------------------------------------------------------------------
__global__ __launch_bounds__(256) void copy_k(const float4* __restrict__ in,
                                              float4* __restrict__ out, long long n) {
    for (long long i = (long long)blockIdx.x * 256 + threadIdx.x; i < n;
         i += (long long)gridDim.x * 256)
        out[i] = in[i];
}

// ---------------------------------------------------------------------------
// Fused flash attention (non-causal, mask==0, S=1024, D=128).
//   Grid: (S/128, NB*NH). Block: 256 thr = 4 waves; wave w owns Q rows
//   [q0+32w, q0+32w+32). Online softmax in exp2 domain (v_exp_f32 is
//   natively 2^x): s' = s * (1/sqrt(128) * log2 e); p = exp2(s'-m').
//   setprio(1) around MFMA clusters (T5).
// ---------------------------------------------------------------------------
__global__ __launch_bounds__(256, 2) void flash_k(
    const bf16* __restrict__ Qr,   // [(b*16+h)][t][128]
    const bf16* __restrict__ Kr,   // [(b*16+h)][t][128]
    const bf16* __restrict__ Vt,   // [(b*16+h)][d][1024]
    bf16* __restrict__ O) {        // [b*NT+t][ND], col h*128+d
    __shared__ char lds[81920];    // K: 2x16K @0, V: 2x16K @32768, P: 4x4K @65536

    const int tid = threadIdx.x;
    const int lane = tid & 63;
    const int w = tid >> 6;
    const int lm = lane & 15, lq = lane >> 4;
    const int lm7 = lm & 7;

    const int bh = blockIdx.y;
    const int q0 = blockIdx.x * 128;
    const bf16* Qb = Qr + (size_t)bh * NT * NHD;
    const bf16* Kb = Kr + (size_t)bh * NT * NHD;
    const bf16* Vb = Vt + (size_t)bh * NHD * NT;

    const int krow = tid >> 4;
    const int kc_s = (tid & 15);
    const int vrow = tid >> 3;
    const int vc_s = (tid & 7);

    bf16x8 q[2][4];
#pragma unroll
    for (int mi = 0; mi < 2; mi++)
#pragma unroll
        for (int ks = 0; ks < 4; ks++)
            q[mi][ks] = *(const bf16x8*)(Qb + (size_t)(q0 + w * 32 + mi * 16 + lm) * NHD
                                         + lq * 8 + ks * 32);

    f32x4 o0[8], o1[8];
#pragma unroll
    for (int i = 0; i < 8; i++) {
        f32x4 zz = {0.f, 0.f, 0.f, 0.f};
        o0[i] = zz; o1[i] = zz;
    }
    float m0[4], m1[4], l0[4], l1[4];
#pragma unroll
    for (int r = 0; r < 4; r++) {
        m0[r] = -3.0e38f; m1[r] = -3.0e38f; l0[r] = 0.f; l1[r] = 0.f;
    }

    char* Pb = lds + 65536 + w * 4096;
    // 1/sqrt(128) * log2(e): softmax in exp2 domain
    const float kscal = 0.08838834764831845f * 1.4426950408889634f;

#pragma unroll
    for (int i = 0; i < 4; i++) {
        int row = i * 16 + krow;
        __builtin_amdgcn_global_load_lds(
            (gptr_t)(Kb + (size_t)row * NHD + (kc_s ^ (row & 7)) * 8),
            (lptr_t)(lds + i * 4096 + tid * 16), 16, 0, 0);
    }
#pragma unroll
    for (int i = 0; i < 4; i++) {
        int row = i * 32 + vrow;
        __builtin_amdgcn_global_load_lds(
            (gptr_t)(Vb + (size_t)row * NT + (vc_s ^ (row & 7)) * 8),
            (lptr_t)(lds + 32768 + i * 4096 + tid * 16), 16, 0, 0);
    }
    __syncthreads();

    for (int c = 0; c < 16; ++c) {
        char* Kl = lds + (c & 1) * 16384;
        char* Vl = lds + 32768 + (c & 1) * 16384;

        if (c < 15) {
            const int key1 = (c + 1) * 64;
            char* Kd = lds + ((c + 1) & 1) * 16384;
            char* Vd = lds + 32768 + ((c + 1) & 1) * 16384;
#pragma unroll
            for (int i = 0; i < 4; i++) {
                int row = i * 16 + krow;
                __builtin_amdgcn_global_load_lds(
                    (gptr_t)(Kb + (size_t)(key1 + row) * NHD + (kc_s ^ (row & 7)) * 8),
                    (lptr_t)(Kd + i * 4096 + tid * 16), 16, 0, 0);
            }
#pragma unroll
            for (int i = 0; i < 4; i++) {
                int row = i * 32 + vrow;
                __builtin_amdgcn_global_load_lds(
                    (gptr_t)(Vb + (size_t)row * NT + key1 + (vc_s ^ (row & 7)) * 8),
                    (lptr_t)(Vd + i * 4096 + tid * 16), 16, 0, 0);
            }
        }

        // ---- QK^T ----
        f32x4 s0[4], s1[4];
#pragma unroll
        for (int ni = 0; ni < 4; ni++) {
            f32x4 zz = {0.f, 0.f, 0.f, 0.f};
            s0[ni] = zz; s1[ni] = zz;
        }
        __builtin_amdgcn_s_setprio(1);
#pragma unroll
        for (int ni = 0; ni < 4; ni++) {
#pragma unroll
            for (int ks = 0; ks < 4; ks++) {
                bf16x8 kf = *(const bf16x8*)(Kl + (lm + 16 * ni) * 256
                                             + (((lq + 4 * ks) ^ lm7) << 4));
                s0[ni] = __builtin_amdgcn_mfma_f32_16x16x32_bf16(q[0][ks], kf, s0[ni], 0, 0, 0);
                s1[ni] = __builtin_amdgcn_mfma_f32_16x16x32_bf16(q[1][ks], kf, s1[ni], 0, 0, 0);
            }
        }
        __builtin_amdgcn_s_setprio(0);

        // ---- scale to exp2 domain once ----
#pragma unroll
        for (int ni = 0; ni < 4; ni++)
#pragma unroll
            for (int r = 0; r < 4; r++) {
                s0[ni][r] *= kscal;
                s1[ni][r] *= kscal;
            }

        // ---- online softmax (exp2 domain) ----
        float sc0[4], sc1[4];
#pragma unroll
        for (int r = 0; r < 4; r++) {
            float a0 = fmaxf(fmaxf(s0[0][r], s0[1][r]), fmaxf(s0[2][r], s0[3][r]));
            float a1 = fmaxf(fmaxf(s1[0][r], s1[1][r]), fmaxf(s1[2][r], s1[3][r]));
#pragma unroll
            for (int o = 1; o < 16; o <<= 1) {
                a0 = fmaxf(a0, __shfl_xor(a0, o));
                a1 = fmaxf(a1, __shfl_xor(a1, o));
            }
            float mn0 = fmaxf(m0[r], a0);
            float mn1 = fmaxf(m1[r], a1);
            sc0[r] = exp2f(m0[r] - mn0);
            sc1[r] = exp2f(m1[r] - mn1);
            m0[r] = mn0; m1[r] = mn1;

            float rs0 = 0.f, rs1 = 0.f;
#pragma unroll
            for (int ni = 0; ni < 4; ni++) {
                float p0 = exp2f(s0[ni][r] - mn0);
                float p1 = exp2f(s1[ni][r] - mn1);
                s0[ni][r] = p0; s1[ni][r] = p1;
                rs0 += p0; rs1 += p1;
            }
#pragma unroll
            for (int o = 1; o < 16; o <<= 1) {
                rs0 += __shfl_xor(rs0, o);
                rs1 += __shfl_xor(rs1, o);
            }
            l0[r] = l0[r] * sc0[r] + rs0;
            l1[r] = l1[r] * sc1[r] + rs1;
        }
#pragma unroll
        for (int ni = 0; ni < 8; ni++)
#pragma unroll
            for (int r = 0; r < 4; r++) {
                o0[ni][r] *= sc0[r];
                o1[ni][r] *= sc1[r];
            }

        // ---- P -> wave-private LDS (bf16, swizzled rows of 128 B) ----
#pragma unroll
        for (int ni = 0; ni < 4; ni++)
#pragma unroll
            for (int r = 0; r < 4; r++) {
                int q_l0 = lq * 4 + r;
                int q_l1 = 16 + q_l0;
                int cw = (lm >> 3) + 2 * ni;
                *(bf16*)(Pb + q_l0 * 128 + ((cw ^ (q_l0 & 7)) << 4) + (lm7 << 1)) =
                    (bf16)s0[ni][r];
                *(bf16*)(Pb + q_l1 * 128 + ((cw ^ (q_l1 & 7)) << 4) + (lm7 << 1)) =
                    (bf16)s1[ni][r];
            }
        asm volatile("s_waitcnt lgkmcnt(0)" ::: "memory");
        __builtin_amdgcn_sched_barrier(0);

        // ---- PV ----
        __builtin_amdgcn_s_setprio(1);
#pragma unroll
        for (int ks = 0; ks < 2; ks++) {
            bf16x8 pa0 = *(const bf16x8*)(Pb + lm * 128 + (((lq + 4 * ks) ^ lm7) << 4));
            bf16x8 pa1 = *(const bf16x8*)(Pb + (lm + 16) * 128 + (((lq + 4 * ks) ^ lm7) << 4));
#pragma unroll
            for (int ni = 0; ni < 8; ni++) {
                bf16x8 vf = *(const bf16x8*)(Vl + (lm + 16 * ni) * 128
                                             + (((lq + 4 * ks) ^ lm7) << 4));
                o0[ni] = __builtin_amdgcn_mfma_f32_16x16x32_bf16(pa0, vf, o0[ni], 0, 0, 0);
                o1[ni] = __builtin_amdgcn_mfma_f32_16x16x32_bf16(pa1, vf, o1[ni], 0, 0, 0);
            }
        }
        __builtin_amdgcn_s_setprio(0);

        __syncthreads();
    }

    // ---- epilogue ----
    const int bb = bh >> 4, h = bh & 15;
    float rl0[4], rl1[4];
#pragma unroll
    for (int r = 0; r < 4; r++) { rl0[r] = 1.f / l0[r]; rl1[r] = 1.f / l1[r]; }
#pragma unroll
    for (int ni = 0; ni < 8; ni++) {
#pragma unroll
        for (int r = 0; r < 4; r++) {
            int col = h * 128 + lm + 16 * ni;
            long long r0 = (long long)bb * NT + q0 + w * 32 + lq * 4 + r;
            O[(r0) * ND + col]      = (bf16)(o0[ni][r] * rl0[r]);
            O[(r0 + 16) * ND + col] = (bf16)(o1[ni][r] * rl1[r]);
        }
    }
}

// ---------------------------------------------------------------------------
// 256-wide 8-phase pipelined GEMM (T2+T3+T4+T5), L2-aware 2D XCD mapping.
//   MODE 0: C bf16 = alpha*acc (256-N tile)
//   MODE 2: C fp32 atomic += acc (256-N, split-K via blockIdx.z)
//   MODE 5: out[(b*NS+sel[m])*ND+n] atomic += rw[m]*(acc+(z==0)*res) (256-N)
//   MODE 6: dual-B (Bt=w1_t, Bt2=w3_t), 128-N tile per matrix;
//           C bf16 = silu(acc1)*acc3  (fused FFN up-projection)
// ---------------------------------------------------------------------------
#define G256_BAR() do { __builtin_amdgcn_sched_barrier(0); \
    __builtin_amdgcn_s_barrier(); __builtin_amdgcn_sched_barrier(0); } while (0)
#define G256_LGKM0() do { asm volatile("s_waitcnt lgkmcnt(0)" ::: "memory"); \
    __builtin_amdgcn_sched_barrier(0); } while (0)
#define G256_VMC(n) do { asm volatile("s_waitcnt vmcnt(" #n ")" ::: "memory"); \
    __builtin_amdgcn_sched_barrier(0); } while (0)

#define STAGE_A(c, h, t) do { \
    char* _l = sm + (c) * 65536 + (h) * 16384 + sdst; \
    long long _ko = (long long)(t) * 64; \
    __builtin_amdgcn_global_load_lds((gptr_t)(gA + (2 * (h)) * stA + _ko), \
                                     (lptr_t)_l, 16, 0, 0); \
    __builtin_amdgcn_global_load_lds((gptr_t)(gA + (2 * (h) + 1) * stA + _ko), \
                                     (lptr_t)(_l + 8192), 16, 0, 0); \
} while (0)
#define STAGE_B(c, h, t) do { \
    char* _l = sm + (c) * 65536 + 32768 + (h) * 16384 + sdst; \
    long long _ko = (long long)(t) * 64; \
    const bf16* _g = (h) ? gBhi : gBlo; \
    __builtin_amdgcn_global_load_lds((gptr_t)(_g + _ko), \
                                     (lptr_t)_l, 16, 0, 0); \
    __builtin_amdgcn_global_load_lds((gptr_t)(_g + stB + _ko), \
                                     (lptr_t)(_l + 8192), 16, 0, 0); \
} while (0)

#define LDA_HALF(c, lo) do { \
    char* _b = sm + (c) * 65536; \
    _Pragma("unroll") \
    for (int _mi = 0; _mi < 4; _mi++) { \
        a[(lo) + _mi][0] = *(const bf16x8*)(_b + aoff + ((lo) + _mi) * 2048); \
        a[(lo) + _mi][1] = *(const bf16x8*)(_b + (aoff ^ 64) + ((lo) + _mi) * 2048); \
    } \
} while (0)
#define LDB_HALF(c, lo) do { \
    char* _b = sm + (c) * 65536 + 32768; \
    _Pragma("unroll") \
    for (int _ni = 0; _ni < 2; _ni++) { \
        int _ix = (lo) + _ni; \
        int _o = boff + (_ix & 1) * 2048 + (_ix >> 1) * bStep2; \
        b[_ix][0] = *(const bf16x8*)(_b + _o); \
        b[_ix][1] = *(const bf16x8*)(_b + (_o ^ 64)); \
    } \
} while (0)

#define MFMA_Q(mlo, nlo) do { \
    __builtin_amdgcn_s_setprio(1); \
    _Pragma("unroll") \
    for (int _ks = 0; _ks < 2; _ks++) \
    _Pragma("unroll") \
    for (int _mi = 0; _mi < 4; _mi++) \
    _Pragma("unroll") \
    for (int _ni = 0; _ni < 2; _ni++) \
        acc[(mlo) + _mi][(nlo) + _ni] = __builtin_amdgcn_mfma_f32_16x16x32_bf16( \
            a[(mlo) + _mi][_ks], b[(nlo) + _ni][_ks], acc[(mlo) + _mi][(nlo) + _ni], \
            0, 0, 0); \
    __builtin_amdgcn_s_setprio(0); \
} while (0)

template <int MODE>
__global__ __launch_bounds__(512, 2) void gemm256(
    const bf16* __restrict__ A, int lda,
    const bf16* __restrict__ Bt, int ldb,
    void* __restrict__ Cv, int ldc,
    int K, float alpha,
    const bf16* __restrict__ Bt2,
    const float* __restrict__ res, const int* __restrict__ selp,
    const float* __restrict__ rwp, float* __restrict__ outp) {
    __shared__ char smem[131072];   // buf c: A @ c*65536, B @ c*65536+32768

    constexpr bool DUALB = (MODE == 6);
    constexpr int bStep2 = DUALB ? 16384 : 4096;   // byte offset ni=2 vs ni=0

    const int tid = threadIdx.x;
    const int lane = tid & 63;
    const int wid = tid >> 6;
    const int wm = wid >> 2, wn = wid & 3;     // 2 x 4 waves
    const int lm = lane & 15, lq = lane >> 4;

    // 2D XCD mapping: xcd quadrant (2 in M x 4 in N), 8 x (nx/4) rect inside,
    // M-first so concurrent blocks share B panels. Requires ny==16, nx%4==0.
    const int nx = gridDim.x;
    const int orig = blockIdx.y * nx + blockIdx.x;
    const int xcd = orig & 7;
    const int r_ = orig >> 3;                  // [0, 2*nx)
    const int mi_ = r_ & 7, ni_ = r_ >> 3;     // 8 x (nx/4)
    const int nTile = DUALB ? 128 : 256;
    const int m0 = ((xcd >> 2) * 8 + mi_) * 256;
    const int n0 = ((xcd & 3) * (nx >> 2) + ni_) * nTile;
    const long long kz = (long long)blockIdx.z * K;

    const int srow = tid >> 3;                 // [0,64)
    const int skc = ((tid & 7) ^ (srow & 7)) * 8;
    const bf16* gA = A + (long long)(m0 + srow) * lda + kz + skc;
    const bf16* gBlo = Bt + (long long)(n0 + srow) * ldb + kz + skc;
    const bf16* gBhi = DUALB
        ? Bt2 + (long long)(n0 + srow) * ldb + kz + skc
        : gBlo + (long long)128 * ldb;
    const long long stA = (long long)64 * lda;
    const long long stB = (long long)64 * ldb;

    char* sm = (char*)smem;
    const int sdst = tid * 16;

    const int aoff = (wm * 128 + lm) * 128 + ((lq ^ (lm & 7)) << 4);
    const int boff = ((DUALB ? wn * 32 : wn * 64) + lm) * 128 + ((lq ^ (lm & 7)) << 4);

    f32x4 acc[8][4];
#pragma unroll
    for (int i = 0; i < 8; i++)
#pragma unroll
        for (int j = 0; j < 4; j++) {
            f32x4 zz = {0.f, 0.f, 0.f, 0.f};
            acc[i][j] = zz;
        }
    bf16x8 a[8][2], b[4][2];

    const int NTk = K >> 6;   // even, >= 16 for all launches here

    STAGE_A(0, 0, 0); STAGE_A(0, 1, 0);
    STAGE_B(0, 0, 0); STAGE_B(0, 1, 0);
    STAGE_A(1, 0, 1); STAGE_A(1, 1, 1);
    G256_VMC(4);
    G256_BAR();

    for (int t0 = 0; t0 < NTk; t0 += 2) {
        const int t1 = t0 + 1, t2 = t0 + 2, t3 = t0 + 3;
        const bool more = (t2 < NTk);

        // ---- K-tile t0 (buf 0) ----
        LDA_HALF(0, 0); LDB_HALF(0, 0);
        STAGE_B(1, 0, t1);
        G256_BAR(); G256_LGKM0(); MFMA_Q(0, 0); G256_BAR();
        LDA_HALF(0, 4);
        STAGE_B(1, 1, t1);
        G256_BAR(); G256_LGKM0(); MFMA_Q(4, 0); G256_BAR();
        LDB_HALF(0, 2);
        if (more) STAGE_A(0, 0, t2);
        G256_BAR(); G256_LGKM0(); MFMA_Q(0, 2); G256_BAR();
        if (more) STAGE_A(0, 1, t2);
        G256_BAR(); G256_LGKM0(); MFMA_Q(4, 2);
        if (more) { G256_VMC(4); } else { G256_VMC(0); }
        G256_BAR();

        // ---- K-tile t1 (buf 1) ----
        LDA_HALF(1, 0); LDB_HALF(1, 0);
        if (more) STAGE_B(0, 0, t2);
        G256_BAR(); G256_LGKM0(); MFMA_Q(0, 0); G256_BAR();
        LDA_HALF(1, 4);
        if (more) STAGE_B(0, 1, t2);
        G256_BAR(); G256_LGKM0(); MFMA_Q(4, 0); G256_BAR();
        LDB_HALF(1, 2);
        if (more) STAGE_A(1, 0, t3);
        G256_BAR(); G256_LGKM0(); MFMA_Q(0, 2); G256_BAR();
        if (more) STAGE_A(1, 1, t3);
        G256_BAR(); G256_LGKM0(); MFMA_Q(4, 2);
        if (more) { G256_VMC(4); } else { G256_VMC(0); }
        G256_BAR();
    }

    if constexpr (MODE == 6) {
        bf16* C = (bf16*)Cv;
#pragma unroll
        for (int mi = 0; mi < 8; mi++) {
#pragma unroll
            for (int ni = 0; ni < 2; ni++) {
                const int row = m0 + wm * 128 + mi * 16 + lq * 4;
                const int col = n0 + wn * 32 + ni * 16 + lm;
#pragma unroll
                for (int r = 0; r < 4; r++) {
                    float v1 = acc[mi][ni][r];
                    float v3 = acc[mi][ni + 2][r];
                    C[(long long)(row + r) * ldc + col] =
                        (bf16)((v1 / (1.f + __expf(-v1))) * v3);
                }
            }
        }
    } else {
#pragma unroll
        for (int mi = 0; mi < 8; mi++) {
#pragma unroll
            for (int ni = 0; ni < 4; ni++) {
                const int row = m0 + wm * 128 + mi * 16 + lq * 4;
                const int col = n0 + wn * 64 + ni * 16 + lm;
#pragma unroll
                for (int r = 0; r < 4; r++) {
                    float v = alpha * acc[mi][ni][r];
                    long long rr = row + r;
                    if constexpr (MODE == 0) {
                        bf16* C = (bf16*)Cv;
                        C[rr * ldc + col] = (bf16)v;
                    } else if constexpr (MODE == 2) {
                        float* C = (float*)Cv;
                        unsafeAtomicAdd(&C[rr * ldc + col], v);
                    } else {   // MODE 5
                        int bb2 = (int)(rr >> 10);
                        int s = selp[rr];
                        float add = rwp[rr] *
                            (v + (blockIdx.z == 0 ? res[rr * (long long)ND + col] : 0.f));
                        unsafeAtomicAdd(outp + ((long long)bb2 * NS + s) * ND + col, add);
                    }
                }
            }
        }
    }
}

// ---------------------------------------------------------------------------
extern "C" void kernel_launch(void* const* d_in, const int* in_sizes, int n_in,
                              void* d_out, int out_size, void* d_ws, size_t ws_size,
                              hipStream_t stream) {
    const float* x  = (const float*)d_in[0];
    const float* fr = (const float*)d_in[2];
    const float* wr = (const float*)d_in[3];
    const float* g1 = (const float*)d_in[4];
    const float* wq = (const float*)d_in[5];
    const float* wk = (const float*)d_in[6];
    const float* wv = (const float*)d_in[7];
    const float* wo = (const float*)d_in[8];
    const float* g2 = (const float*)d_in[9];
    const float* w1 = (const float*)d_in[10];
    const float* w3 = (const float*)d_in[11];
    const float* w2 = (const float*)d_in[12];
    float* out = (float*)d_out;

    char* ws = (char*)d_ws;
    size_t off = 0;
    auto take = [&](size_t bytes) -> char* {
        char* p = ws + off;
        off += (bytes + 255) & ~(size_t)255;
        return p;
    };
    int*   sel    = (int*)take((size_t)NB * NT * 4);
    float* rw     = (float*)take((size_t)NB * NT * 4);
    float* logits = (float*)take((size_t)NB * NS * 4);
    float* xf     = (float*)take((size_t)NB * NT * ND * 4);
    bf16*  hbuf   = (bf16*)take((size_t)NB * NT * ND * 2);
    bf16*  wqkv_t = (bf16*)take((size_t)3 * ND * ND * 2);
    bf16*  wo_t   = (bf16*)take((size_t)ND * ND * 2);
    bf16*  Obuf   = (bf16*)take((size_t)NB * NT * ND * 2);
    char* xr = ws + off;
    // attention-phase overlay
    bf16* QKV = (bf16*)xr;                               // [4096][6144]
    bf16* Qr  = QKV + (size_t)NB * NT * 3 * ND;
    bf16* Kr  = Qr + (size_t)NB * NT * ND;
    bf16* Vt  = Kr + (size_t)NB * NT * ND;
    // FFN-phase overlay (attention data dead by then)
    bf16* w1_t  = (bf16*)xr;
    bf16* w3_t  = w1_t + (size_t)ND * NF;
    bf16* w2_t  = w3_t + (size_t)ND * NF;
    bf16* inter = w2_t + (size_t)ND * NF;

    router_k<<<NB * NS, 256, 0, stream>>>(x, wr, logits);
    topk_k<<<NB, 1024, 0, stream>>>(logits, sel, rw);
    gather_k<<<(NB * NT * ND / 4) / 256, 256, 0, stream>>>(x, sel, xf);
    rmsnorm_k<<<NB * NT, 256, 0, stream>>>(xf, g1, hbuf);

    dim3 tg(ND / 32, ND / 32);
    transpose_to_bf16<<<tg, 256, 0, stream>>>(wq, wqkv_t, ND, ND);
    transpose_to_bf16<<<tg, 256, 0, stream>>>(wk, wqkv_t + (size_t)ND * ND, ND, ND);
    transpose_to_bf16<<<tg, 256, 0, stream>>>(wv, wqkv_t + (size_t)2 * ND * ND, ND, ND);
    transpose_to_bf16<<<tg, 256, 0, stream>>>(wo, wo_t, ND, ND);

    // fused QKV: [4096 x 2048] x [6144 x 2048]^T -> [4096][6144]
    gemm256<0><<<dim3(3 * ND / 256, NB * NT / 256, 1), 512, 0, stream>>>(
        hbuf, ND, wqkv_t, ND, QKV, 3 * ND, ND, 1.0f,
        nullptr, nullptr, nullptr, nullptr, nullptr);

    rope_qk_k<<<(NB * NT * NH * 64) / 256, 256, 0, stream>>>(QKV, fr, Qr, Kr);
    vtr_k<<<dim3(NT / 64, NB * NH), 256, 0, stream>>>(QKV, Vt);

    // fused flash attention: replaces QK^T gemm + softmax + PV gemm
    flash_k<<<dim3(NT / 128, NB * NH), 256, 0, stream>>>(Qr, Kr, Vt, Obuf);

    // WO: split-K x2 (K=1024 each), atomic += into xf residual
    gemm256<2><<<dim3(ND / 256, NB * NT / 256, 2), 512, 0, stream>>>(
        Obuf, ND, wo_t, ND, xf, ND, ND / 2, 1.0f,
        nullptr, nullptr, nullptr, nullptr, nullptr);

    rmsnorm_k<<<NB * NT, 256, 0, stream>>>(xf, g2, hbuf);

    transpose_to_bf16<<<dim3(NF / 32, ND / 32), 256, 0, stream>>>(w1, w1_t, ND, NF);
    transpose_to_bf16<<<dim3(NF / 32, ND / 32), 256, 0, stream>>>(w3, w3_t, ND, NF);
    transpose_to_bf16<<<dim3(ND / 32, NF / 32), 256, 0, stream>>>(w2, w2_t, NF, ND);

    // fused FFN up: inter = silu(h.w1) * (h.w3), one dual-B dispatch
    gemm256<6><<<dim3(NF / 128, NB * NT / 256, 1), 512, 0, stream>>>(
        hbuf, ND, w1_t, ND, inter, NF, ND, 1.0f,
        w3_t, nullptr, nullptr, nullptr, nullptr);

    copy_k<<<8192, 256, 0, stream>>>((const float4*)x, (float4*)out,
                                     (long long)NB * NS * ND / 4);
    // w2 + scatter-add: split-K x2 (K=4096 each), res added on z==0 only
    gemm256<5><<<dim3(ND / 256, NB * NT / 256, 2), 512, 0, stream>>>(
        inter, NF, w2_t, NF, nullptr, ND, NF / 2, 1.0f,
        nullptr, xf, sel, rw, out);
}

// Round 7
// 1233.961 us; speedup vs baseline: 1.2550x; 1.0529x over previous
//
#include <hip/hip_runtime.h>
#include <cstdint>
#include <cstddef>

#define NB 4
#define NS 4096
#define ND 2048
#define NH 16
#define NHD 128
#define NT 1024
#define NF 8192

typedef __bf16 bf16;
typedef __bf16 bf16x8 __attribute__((ext_vector_type(8)));
typedef __bf16 bf16x4 __attribute__((ext_vector_type(4)));
typedef float  f32x4  __attribute__((ext_vector_type(4)));

typedef const __attribute__((address_space(1))) void* gptr_t;
typedef __attribute__((address_space(3))) void* lptr_t;

__device__ __forceinline__ float wave_sum(float v) {
#pragma unroll
    for (int off = 32; off > 0; off >>= 1) v += __shfl_xor(v, off);
    return v;
}
__device__ __forceinline__ float wave_max(float v) {
#pragma unroll
    for (int off = 32; off > 0; off >>= 1) v = fmaxf(v, __shfl_xor(v, off));
    return v;
}

// ---------------------------------------------------------------------------
// Router: logits[row] = dot(x[row,:], w_router)   (row = b*NS+s)
// ---------------------------------------------------------------------------
__global__ __launch_bounds__(256) void router_k(const float* __restrict__ x,
                                                const float* __restrict__ wr,
                                                float* __restrict__ logits) {
    __shared__ float r4[4];
    long long row = blockIdx.x;
    const float4* xr = (const float4*)(x + row * ND);
    const float4* w4 = (const float4*)wr;
    float p = 0.f;
    for (int i = threadIdx.x; i < ND / 4; i += 256) {
        float4 a = xr[i], b = w4[i];
        p += a.x * b.x + a.y * b.y + a.z * b.z + a.w * b.w;
    }
    p = wave_sum(p);
    if ((threadIdx.x & 63) == 0) r4[threadIdx.x >> 6] = p;
    __syncthreads();
    if (threadIdx.x == 0) logits[row] = r4[0] + r4[1] + r4[2] + r4[3];
}

// ---------------------------------------------------------------------------
// Top-K (exact, matches jax.lax.top_k tie-break) + index sort + router softmax.
// ---------------------------------------------------------------------------
__global__ __launch_bounds__(1024) void topk_k(const float* __restrict__ logits,
                                               int* __restrict__ sel,
                                               float* __restrict__ rw) {
    __shared__ unsigned long long keys[NS];   // 32 KB
    __shared__ float r16[16];
    __shared__ float bmax, bsum;
    const int bb = blockIdx.x;
    const int tid = threadIdx.x;
    const float* lg = logits + (long long)bb * NS;

    for (int i = tid; i < NS; i += 1024) {
        unsigned u = __float_as_uint(lg[i]);
        u = (u & 0x80000000u) ? ~u : (u | 0x80000000u);   // order-preserving map
        keys[i] = ((unsigned long long)u << 32) | (unsigned)(NS - 1 - i);
    }
    __syncthreads();
    for (int k = 2; k <= NS; k <<= 1) {
        for (int j = k >> 1; j > 0; j >>= 1) {
            for (int i = tid; i < NS; i += 1024) {
                int ixj = i ^ j;
                if (ixj > i) {
                    unsigned long long a = keys[i], c = keys[ixj];
                    bool up = ((i & k) == 0);
                    if (up ? (a < c) : (a > c)) { keys[i] = c; keys[ixj] = a; }
                }
            }
            __syncthreads();
        }
    }
    unsigned long long a0 = keys[tid];
    __syncthreads();
    {
        unsigned idx_ = NS - 1 - (unsigned)(a0 & 0xFFFFFFFFu);
        unsigned uval = (unsigned)(a0 >> 32);
        keys[tid] = ((unsigned long long)idx_ << 32) | uval;
    }
    __syncthreads();
    for (int k = 2; k <= NT; k <<= 1) {
        for (int j = k >> 1; j > 0; j >>= 1) {
            int i = tid, ixj = i ^ j;
            if (i < NT && ixj > i) {
                unsigned long long a = keys[i], c = keys[ixj];
                bool up = ((i & k) == 0);
                if (up ? (a > c) : (a < c)) { keys[i] = c; keys[ixj] = a; }
            }
            __syncthreads();
        }
    }
    unsigned long long kk = keys[tid];
    int si = (int)(kk >> 32);
    unsigned u = (unsigned)(kk & 0xFFFFFFFFu);
    u = (u & 0x80000000u) ? (u ^ 0x80000000u) : ~u;
    float val = __uint_as_float(u);

    const int wid = tid >> 6, lane = tid & 63;
    float mx = wave_max(val);
    if (lane == 0) r16[wid] = mx;
    __syncthreads();
    if (tid == 0) {
        float m = r16[0];
        for (int i = 1; i < 16; i++) m = fmaxf(m, r16[i]);
        bmax = m;
    }
    __syncthreads();
    float e = __expf(val - bmax);
    float s = wave_sum(e);
    if (lane == 0) r16[wid] = s;
    __syncthreads();
    if (tid == 0) {
        float t = 0.f;
        for (int i = 0; i < 16; i++) t += r16[i];
        bsum = t;
    }
    __syncthreads();
    sel[bb * NT + tid] = si;
    rw[bb * NT + tid] = e / bsum;
}

// ---------------------------------------------------------------------------
// Gather: xf[b,j,:] = x[b, sel[b,j], :]   (float4)
// ---------------------------------------------------------------------------
__global__ __launch_bounds__(256) void gather_k(const float* __restrict__ x,
                                                const int* __restrict__ sel,
                                                float* __restrict__ xf) {
    int gid = blockIdx.x * 256 + threadIdx.x;
    int col = gid & (ND / 4 - 1);
    int row = gid >> 9;
    int bb = row >> 10;
    int s = sel[row];
    ((float4*)xf)[gid] = ((const float4*)x)[((long long)bb * NS + s) * (ND / 4) + col];
}

// ---------------------------------------------------------------------------
// RMSNorm row kernel: out = bf16(x * rsqrt(mean(x^2)+eps) * g)
// ---------------------------------------------------------------------------
__global__ __launch_bounds__(256) void rmsnorm_k(const float* __restrict__ x,
                                                 const float* __restrict__ g,
                                                 bf16* __restrict__ out) {
    __shared__ float r4[4];
    __shared__ float scl;
    long long row = blockIdx.x;
    const float4* xr = (const float4*)(x + row * ND);
    int i0 = threadIdx.x, i1 = threadIdx.x + 256;
    float4 a = xr[i0], b = xr[i1];
    float ss = a.x * a.x + a.y * a.y + a.z * a.z + a.w * a.w +
               b.x * b.x + b.y * b.y + b.z * b.z + b.w * b.w;
    ss = wave_sum(ss);
    if ((threadIdx.x & 63) == 0) r4[threadIdx.x >> 6] = ss;
    __syncthreads();
    if (threadIdx.x == 0)
        scl = rsqrtf((r4[0] + r4[1] + r4[2] + r4[3]) * (1.0f / ND) + 1e-6f);
    __syncthreads();
    float s = scl;
    const float4* g4 = (const float4*)g;
    float4 ga = g4[i0], gb = g4[i1];
    bf16x4 o0, o1;
    o0[0] = (bf16)(a.x * s * ga.x); o0[1] = (bf16)(a.y * s * ga.y);
    o0[2] = (bf16)(a.z * s * ga.z); o0[3] = (bf16)(a.w * s * ga.w);
    o1[0] = (bf16)(b.x * s * gb.x); o1[1] = (bf16)(b.y * s * gb.y);
    o1[2] = (bf16)(b.z * s * gb.z); o1[3] = (bf16)(b.w * s * gb.w);
    *(bf16x4*)(out + row * ND + i0 * 4) = o0;
    *(bf16x4*)(out + row * ND + i1 * 4) = o1;
}

// ---------------------------------------------------------------------------
// Transpose + fp32->bf16: out[c][r] = in[r][c]; in is R x C. dims %32 == 0.
// ---------------------------------------------------------------------------
__global__ __launch_bounds__(256) void transpose_to_bf16(const float* __restrict__ in,
                                                         bf16* __restrict__ out,
                                                         int R, int C) {
    __shared__ float tile[32][33];
    int bx = blockIdx.x * 32;   // col
    int by = blockIdx.y * 32;   // row
    int tx = threadIdx.x & 31;
    int ty = threadIdx.x >> 5;   // 0..7
#pragma unroll
    for (int i = 0; i < 4; i++)
        tile[ty + 8 * i][tx] = in[(long long)(by + ty + 8 * i) * C + bx + tx];
    __syncthreads();
#pragma unroll
    for (int i = 0; i < 4; i++)
        out[(long long)(bx + ty + 8 * i) * R + by + tx] = (bf16)tile[tx][ty + 8 * i];
}

// ---------------------------------------------------------------------------
// RoPE for Q,K only (reads fused QKV buffer, row stride 3*ND). Coalesced.
// ---------------------------------------------------------------------------
__global__ __launch_bounds__(256) void rope_qk_k(const bf16* __restrict__ QKV,
                                                 const float* __restrict__ fr,
                                                 bf16* __restrict__ Q,
                                                 bf16* __restrict__ K) {
    int gid = blockIdx.x * 256 + threadIdx.x;
    int hd = gid & 63;
    int h = (gid >> 6) & 15;
    int t = (gid >> 10) & (NT - 1);
    int bb = gid >> 20;
    float c = fr[t * 128 + hd * 2 + 0];
    float s = fr[t * 128 + hd * 2 + 1];
    long long base = ((long long)bb * NT + t) * (3 * ND) + h * NHD;
    float q1 = (float)QKV[base + hd],      q2 = (float)QKV[base + hd + 64];
    float k1 = (float)QKV[base + ND + hd], k2 = (float)QKV[base + ND + hd + 64];
    long long ob = (((long long)(bb * NH + h)) * NT + t) * NHD;
    Q[ob + hd]      = (bf16)(q1 * c - q2 * s);
    Q[ob + hd + 64] = (bf16)(q1 * s + q2 * c);
    K[ob + hd]      = (bf16)(k1 * c - k2 * s);
    K[ob + hd + 64] = (bf16)(k1 * s + k2 * c);
}

// ---------------------------------------------------------------------------
// V transpose via LDS tile: Vt[(b*16+h)][d][t] = QKV[b*NT+t][2*ND + h*128 + d].
// ---------------------------------------------------------------------------
__global__ __launch_bounds__(256) void vtr_k(const bf16* __restrict__ QKV,
                                             bf16* __restrict__ Vt) {
    __shared__ bf16 tile[64][136];   // padded: row stride 272B
    const int tt = blockIdx.x * 64;
    const int bh = blockIdx.y;
    const int bb = bh >> 4, h = bh & 15;
    const int tid = threadIdx.x;

    const int lt = tid >> 4;            // 0..15
    const int ld = (tid & 15) * 8;      // d-octet
#pragma unroll
    for (int i = 0; i < 4; i++) {
        int t = i * 16 + lt;
        bf16x8 v = *(const bf16x8*)(QKV + ((size_t)(bb * NT) + tt + t) * (3 * ND)
                                    + 2 * ND + h * NHD + ld);
        *(bf16x8*)&tile[t][ld] = v;
    }
    __syncthreads();

    const int d = tid >> 1;             // 0..127
    const int j0 = (tid & 1) * 32;      // t-half
    bf16 tmp[32];
#pragma unroll
    for (int j = 0; j < 32; j++) tmp[j] = tile[j0 + j][d];
    bf16* dst = Vt + ((size_t)bh * NHD + d) * NT + tt + j0;
#pragma unroll
    for (int j = 0; j < 4; j++)
        *(bf16x8*)(dst + j * 8) = *(const bf16x8*)(tmp + j * 8);
}

// ---------------------------------------------------------------------------
__global__ __launch_bounds__(256) void copy_k(const float4* __restrict__ in,
                                              float4* __restrict__ out, long long n) {
    for (long long i = (long long)blockIdx.x * 256 + threadIdx.x; i < n;
         i += (long long)gridDim.x * 256)
        out[i] = in[i];
}

// ---------------------------------------------------------------------------
// Fused flash attention (non-causal, mask==0, S=1024, D=128). Unchanged r6.
// ---------------------------------------------------------------------------
__global__ __launch_bounds__(256, 2) void flash_k(
    const bf16* __restrict__ Qr,   // [(b*16+h)][t][128]
    const bf16* __restrict__ Kr,   // [(b*16+h)][t][128]
    const bf16* __restrict__ Vt,   // [(b*16+h)][d][1024]
    bf16* __restrict__ O) {        // [b*NT+t][ND], col h*128+d
    __shared__ char lds[81920];    // K: 2x16K @0, V: 2x16K @32768, P: 4x4K @65536

    const int tid = threadIdx.x;
    const int lane = tid & 63;
    const int w = tid >> 6;
    const int lm = lane & 15, lq = lane >> 4;
    const int lm7 = lm & 7;

    const int bh = blockIdx.y;
    const int q0 = blockIdx.x * 128;
    const bf16* Qb = Qr + (size_t)bh * NT * NHD;
    const bf16* Kb = Kr + (size_t)bh * NT * NHD;
    const bf16* Vb = Vt + (size_t)bh * NHD * NT;

    const int krow = tid >> 4;
    const int kc_s = (tid & 15);
    const int vrow = tid >> 3;
    const int vc_s = (tid & 7);

    bf16x8 q[2][4];
#pragma unroll
    for (int mi = 0; mi < 2; mi++)
#pragma unroll
        for (int ks = 0; ks < 4; ks++)
            q[mi][ks] = *(const bf16x8*)(Qb + (size_t)(q0 + w * 32 + mi * 16 + lm) * NHD
                                         + lq * 8 + ks * 32);

    f32x4 o0[8], o1[8];
#pragma unroll
    for (int i = 0; i < 8; i++) {
        f32x4 zz = {0.f, 0.f, 0.f, 0.f};
        o0[i] = zz; o1[i] = zz;
    }
    float m0[4], m1[4], l0[4], l1[4];
#pragma unroll
    for (int r = 0; r < 4; r++) {
        m0[r] = -3.0e38f; m1[r] = -3.0e38f; l0[r] = 0.f; l1[r] = 0.f;
    }

    char* Pb = lds + 65536 + w * 4096;
    const float kscal = 0.08838834764831845f * 1.4426950408889634f;

#pragma unroll
    for (int i = 0; i < 4; i++) {
        int row = i * 16 + krow;
        __builtin_amdgcn_global_load_lds(
            (gptr_t)(Kb + (size_t)row * NHD + (kc_s ^ (row & 7)) * 8),
            (lptr_t)(lds + i * 4096 + tid * 16), 16, 0, 0);
    }
#pragma unroll
    for (int i = 0; i < 4; i++) {
        int row = i * 32 + vrow;
        __builtin_amdgcn_global_load_lds(
            (gptr_t)(Vb + (size_t)row * NT + (vc_s ^ (row & 7)) * 8),
            (lptr_t)(lds + 32768 + i * 4096 + tid * 16), 16, 0, 0);
    }
    __syncthreads();

    for (int c = 0; c < 16; ++c) {
        char* Kl = lds + (c & 1) * 16384;
        char* Vl = lds + 32768 + (c & 1) * 16384;

        if (c < 15) {
            const int key1 = (c + 1) * 64;
            char* Kd = lds + ((c + 1) & 1) * 16384;
            char* Vd = lds + 32768 + ((c + 1) & 1) * 16384;
#pragma unroll
            for (int i = 0; i < 4; i++) {
                int row = i * 16 + krow;
                __builtin_amdgcn_global_load_lds(
                    (gptr_t)(Kb + (size_t)(key1 + row) * NHD + (kc_s ^ (row & 7)) * 8),
                    (lptr_t)(Kd + i * 4096 + tid * 16), 16, 0, 0);
            }
#pragma unroll
            for (int i = 0; i < 4; i++) {
                int row = i * 32 + vrow;
                __builtin_amdgcn_global_load_lds(
                    (gptr_t)(Vb + (size_t)row * NT + key1 + (vc_s ^ (row & 7)) * 8),
                    (lptr_t)(Vd + i * 4096 + tid * 16), 16, 0, 0);
            }
        }

        // ---- QK^T ----
        f32x4 s0[4], s1[4];
#pragma unroll
        for (int ni = 0; ni < 4; ni++) {
            f32x4 zz = {0.f, 0.f, 0.f, 0.f};
            s0[ni] = zz; s1[ni] = zz;
        }
        __builtin_amdgcn_s_setprio(1);
#pragma unroll
        for (int ni = 0; ni < 4; ni++) {
#pragma unroll
            for (int ks = 0; ks < 4; ks++) {
                bf16x8 kf = *(const bf16x8*)(Kl + (lm + 16 * ni) * 256
                                             + (((lq + 4 * ks) ^ lm7) << 4));
                s0[ni] = __builtin_amdgcn_mfma_f32_16x16x32_bf16(q[0][ks], kf, s0[ni], 0, 0, 0);
                s1[ni] = __builtin_amdgcn_mfma_f32_16x16x32_bf16(q[1][ks], kf, s1[ni], 0, 0, 0);
            }
        }
        __builtin_amdgcn_s_setprio(0);

#pragma unroll
        for (int ni = 0; ni < 4; ni++)
#pragma unroll
            for (int r = 0; r < 4; r++) {
                s0[ni][r] *= kscal;
                s1[ni][r] *= kscal;
            }

        float sc0[4], sc1[4];
#pragma unroll
        for (int r = 0; r < 4; r++) {
            float a0 = fmaxf(fmaxf(s0[0][r], s0[1][r]), fmaxf(s0[2][r], s0[3][r]));
            float a1 = fmaxf(fmaxf(s1[0][r], s1[1][r]), fmaxf(s1[2][r], s1[3][r]));
#pragma unroll
            for (int o = 1; o < 16; o <<= 1) {
                a0 = fmaxf(a0, __shfl_xor(a0, o));
                a1 = fmaxf(a1, __shfl_xor(a1, o));
            }
            float mn0 = fmaxf(m0[r], a0);
            float mn1 = fmaxf(m1[r], a1);
            sc0[r] = exp2f(m0[r] - mn0);
            sc1[r] = exp2f(m1[r] - mn1);
            m0[r] = mn0; m1[r] = mn1;

            float rs0 = 0.f, rs1 = 0.f;
#pragma unroll
            for (int ni = 0; ni < 4; ni++) {
                float p0 = exp2f(s0[ni][r] - mn0);
                float p1 = exp2f(s1[ni][r] - mn1);
                s0[ni][r] = p0; s1[ni][r] = p1;
                rs0 += p0; rs1 += p1;
            }
#pragma unroll
            for (int o = 1; o < 16; o <<= 1) {
                rs0 += __shfl_xor(rs0, o);
                rs1 += __shfl_xor(rs1, o);
            }
            l0[r] = l0[r] * sc0[r] + rs0;
            l1[r] = l1[r] * sc1[r] + rs1;
        }
#pragma unroll
        for (int ni = 0; ni < 8; ni++)
#pragma unroll
            for (int r = 0; r < 4; r++) {
                o0[ni][r] *= sc0[r];
                o1[ni][r] *= sc1[r];
            }

#pragma unroll
        for (int ni = 0; ni < 4; ni++)
#pragma unroll
            for (int r = 0; r < 4; r++) {
                int q_l0 = lq * 4 + r;
                int q_l1 = 16 + q_l0;
                int cw = (lm >> 3) + 2 * ni;
                *(bf16*)(Pb + q_l0 * 128 + ((cw ^ (q_l0 & 7)) << 4) + (lm7 << 1)) =
                    (bf16)s0[ni][r];
                *(bf16*)(Pb + q_l1 * 128 + ((cw ^ (q_l1 & 7)) << 4) + (lm7 << 1)) =
                    (bf16)s1[ni][r];
            }
        asm volatile("s_waitcnt lgkmcnt(0)" ::: "memory");
        __builtin_amdgcn_sched_barrier(0);

        __builtin_amdgcn_s_setprio(1);
#pragma unroll
        for (int ks = 0; ks < 2; ks++) {
            bf16x8 pa0 = *(const bf16x8*)(Pb + lm * 128 + (((lq + 4 * ks) ^ lm7) << 4));
            bf16x8 pa1 = *(const bf16x8*)(Pb + (lm + 16) * 128 + (((lq + 4 * ks) ^ lm7) << 4));
#pragma unroll
            for (int ni = 0; ni < 8; ni++) {
                bf16x8 vf = *(const bf16x8*)(Vl + (lm + 16 * ni) * 128
                                             + (((lq + 4 * ks) ^ lm7) << 4));
                o0[ni] = __builtin_amdgcn_mfma_f32_16x16x32_bf16(pa0, vf, o0[ni], 0, 0, 0);
                o1[ni] = __builtin_amdgcn_mfma_f32_16x16x32_bf16(pa1, vf, o1[ni], 0, 0, 0);
            }
        }
        __builtin_amdgcn_s_setprio(0);

        __syncthreads();
    }

    const int bb = bh >> 4, h = bh & 15;
    float rl0[4], rl1[4];
#pragma unroll
    for (int r = 0; r < 4; r++) { rl0[r] = 1.f / l0[r]; rl1[r] = 1.f / l1[r]; }
#pragma unroll
    for (int ni = 0; ni < 8; ni++) {
#pragma unroll
        for (int r = 0; r < 4; r++) {
            int col = h * 128 + lm + 16 * ni;
            long long r0 = (long long)bb * NT + q0 + w * 32 + lq * 4 + r;
            O[(r0) * ND + col]      = (bf16)(o0[ni][r] * rl0[r]);
            O[(r0 + 16) * ND + col] = (bf16)(o1[ni][r] * rl1[r]);
        }
    }
}

// ---------------------------------------------------------------------------
// 256xN pipelined GEMM, counted-lgkmcnt K-loop (2 barriers/K-tile):
//   per K-tile: issue ALL frag ds_reads (order pinned by sched_barrier groups)
//   -> lgkmcnt(12) MFMA Q00 -> lgkmcnt(8) MFMA Q02 -> lgkmcnt(0)
//   -> barrier (release buf) -> stage t+2 -> MFMA Q40+Q42 (overlaps staging)
//   -> vmcnt(GL) -> barrier (t+1 visible). DS returns in-order per wave, so
//   counted lgkm waits are sound; compiler's own waitcnts also guard deps.
//   NTILE=256 (MODE 0/6): 24 reads, 8 gloads/tile, LDS 128K.
//   NTILE=128 (MODE 2/5): 20 reads, 6 gloads/tile, LDS 96K; grid 16x16,
//   single-z, NON-atomic += epilogues (tiles exclusive).
// MODE 0: C bf16 = alpha*acc          MODE 2: C fp32 += acc (exclusive)
// MODE 5: out[(b*NS+sel[m])*ND+n] += rw[m]*(acc+res)   (exclusive)
// MODE 6: dual-B (w1,w3): C bf16 = silu(acc1)*acc3
// ---------------------------------------------------------------------------
#define G256_SB() __builtin_amdgcn_sched_barrier(0)
#define G256_LGKM(n) do { asm volatile("s_waitcnt lgkmcnt(" #n ")" ::: "memory"); \
    __builtin_amdgcn_sched_barrier(0); } while (0)
#define G256_VMC(n) do { asm volatile("s_waitcnt vmcnt(" #n ")" ::: "memory"); \
    __builtin_amdgcn_sched_barrier(0); } while (0)

#define MFMA_Q(mlo, nlo) do { \
    __builtin_amdgcn_s_setprio(1); \
    _Pragma("unroll") \
    for (int _ks = 0; _ks < 2; _ks++) \
    _Pragma("unroll") \
    for (int _mi = 0; _mi < 4; _mi++) \
    _Pragma("unroll") \
    for (int _ni = 0; _ni < 2; _ni++) \
        acc[(mlo) + _mi][(nlo) + _ni] = __builtin_amdgcn_mfma_f32_16x16x32_bf16( \
            a[(mlo) + _mi][_ks], b[(nlo) + _ni][_ks], acc[(mlo) + _mi][(nlo) + _ni], \
            0, 0, 0); \
    __builtin_amdgcn_s_setprio(0); \
} while (0)

template <int MODE>
__global__ __launch_bounds__(512, 2) void gemm256(
    const bf16* __restrict__ A, int lda,
    const bf16* __restrict__ Bt, int ldb,
    void* __restrict__ Cv, int ldc,
    int K, float alpha,
    const bf16* __restrict__ Bt2,
    const float* __restrict__ res, const int* __restrict__ selp,
    const float* __restrict__ rwp, float* __restrict__ outp) {

    constexpr bool DUALB = (MODE == 6);
    constexpr bool N128  = (MODE == 2 || MODE == 5);
    constexpr bool NI4   = !N128;                    // 4 ni-pairs (256 B-rows)
    constexpr int  BBUF  = N128 ? 16384 : 32768;     // B bytes per buffer
    constexpr int  BUFS  = 32768 + BBUF;             // per-buffer bytes
    constexpr int  bw    = (DUALB || N128) ? 32 : 64;   // cols per wave
    constexpr int  bStep2 = DUALB ? 16384 : 4096;    // ni-pair 1 byte offset
    constexpr int  NIE   = (DUALB || N128) ? 2 : 4;  // epilogue ni count
    __shared__ char smem[2 * BUFS];

    const int tid = threadIdx.x;
    const int lane = tid & 63;
    const int wid = tid >> 6;
    const int wm = wid >> 2, wn = wid & 3;     // 2 x 4 waves
    const int lm = lane & 15, lq = lane >> 4;

    // 2D XCD mapping: xcd quadrant (2M x 4N), 8 x (nx/4) rect inside, M-first.
    // Requires ny==16, nx%4==0.
    const int nx = gridDim.x;
    const int orig = blockIdx.y * nx + blockIdx.x;
    const int xcd = orig & 7;
    const int r_ = orig >> 3;
    const int mi_ = r_ & 7, ni_ = r_ >> 3;
    const int nT = (DUALB || N128) ? 128 : 256;
    const int m0 = ((xcd >> 2) * 8 + mi_) * 256;
    const int n0 = ((xcd & 3) * (nx >> 2) + ni_) * nT;
    const long long kz = (long long)blockIdx.z * K;

    // staging: thread stages 16B chunk; LDS linear, global source pre-swizzled
    const int srow = tid >> 3;                 // [0,64)
    const int skc = ((tid & 7) ^ (srow & 7)) * 8;
    const long long stA = (long long)64 * lda;
    const long long stB = (long long)64 * ldb;
    const bf16* gA = A + (long long)(m0 + srow) * lda + kz + skc;
    const bf16* gB0 = Bt + (long long)(n0 + srow) * ldb + kz + skc;
    const bf16* gB2 = DUALB ? Bt2 + (long long)(n0 + srow) * ldb + kz + skc
                            : gB0 + 2 * stB;

    char* sm = (char*)smem;
    const int sdst = tid * 16;

    auto stage = [&](int c, int t) {
        char* lA = sm + c * BUFS + sdst;
        long long ko = (long long)t * 64;
#pragma unroll
        for (int i = 0; i < 4; i++)
            __builtin_amdgcn_global_load_lds((gptr_t)(gA + i * stA + ko),
                                             (lptr_t)(lA + i * 8192), 16, 0, 0);
        char* lB = sm + c * BUFS + 32768 + sdst;
        __builtin_amdgcn_global_load_lds((gptr_t)(gB0 + ko), (lptr_t)lB, 16, 0, 0);
        __builtin_amdgcn_global_load_lds((gptr_t)(gB0 + stB + ko),
                                         (lptr_t)(lB + 8192), 16, 0, 0);
        if constexpr (NI4) {
            __builtin_amdgcn_global_load_lds((gptr_t)(gB2 + ko),
                                             (lptr_t)(lB + 16384), 16, 0, 0);
            __builtin_amdgcn_global_load_lds((gptr_t)(gB2 + stB + ko),
                                             (lptr_t)(lB + 24576), 16, 0, 0);
        }
    };

    // frag read offsets: row*128 + ((ks*4+lq) ^ (lm&7))*16 ; ks=1 is ^64
    const int aoff = (wm * 128 + lm) * 128 + ((lq ^ (lm & 7)) << 4);
    const int boff = (wn * bw + lm) * 128 + ((lq ^ (lm & 7)) << 4);

    f32x4 acc[8][4];
#pragma unroll
    for (int i = 0; i < 8; i++)
#pragma unroll
        for (int j = 0; j < 4; j++) {
            f32x4 zz = {0.f, 0.f, 0.f, 0.f};
            acc[i][j] = zz;
        }
    bf16x8 a[8][2], b[4][2];

    auto ldA4 = [&](char* bA, int lo) {
#pragma unroll
        for (int mi2 = 0; mi2 < 4; mi2++) {
            a[lo + mi2][0] = *(const bf16x8*)(bA + aoff + (lo + mi2) * 2048);
            a[lo + mi2][1] = *(const bf16x8*)(bA + (aoff ^ 64) + (lo + mi2) * 2048);
        }
    };
    auto ldB2 = [&](char* bB, int lo) {
#pragma unroll
        for (int ni2 = 0; ni2 < 2; ni2++) {
            int ix = lo + ni2;
            int o = boff + (ix & 1) * 2048 + (ix >> 1) * bStep2;
            b[ix][0] = *(const bf16x8*)(bB + o);
            b[ix][1] = *(const bf16x8*)(bB + (o ^ 64));
        }
    };

    const int NTk = K >> 6;

    // prologue: stage tile0 -> buf0, tile1 -> buf1; wait tile0
    stage(0, 0);
    stage(1, 1);
    if constexpr (NI4) { G256_VMC(8); } else { G256_VMC(6); }
    __builtin_amdgcn_s_barrier();
    G256_SB();

    for (int t = 0; t < NTk; ++t) {
        const int c = t & 1;
        char* bA = sm + c * BUFS;
        char* bB = bA + 32768;

        // issue all frag reads; group order pinned (counts depend on it)
        ldA4(bA, 0);
        ldB2(bB, 0);           // group1: 12 reads
        G256_SB();
        if constexpr (NI4) {
            ldB2(bB, 2);       // group2: 4 reads
            G256_SB();
        }
        ldA4(bA, 4);           // group3: 8 reads
        G256_SB();

        if constexpr (NI4) { G256_LGKM(12); } else { G256_LGKM(8); }
        MFMA_Q(0, 0);
        if constexpr (NI4) {
            G256_LGKM(8);
            MFMA_Q(0, 2);
        }
        G256_LGKM(0);                        // all reads of buf c done
        __builtin_amdgcn_s_barrier();        // release buf c
        G256_SB();
        const bool more = (t + 2 < NTk);
        if (more) stage(c, t + 2);           // overwrite buf c with t+2
        G256_SB();
        MFMA_Q(4, 0);                        // overlaps staging issue/latency
        if constexpr (NI4) MFMA_Q(4, 2);
        if (more) {
            if constexpr (NI4) { G256_VMC(8); } else { G256_VMC(6); }
        } else {
            G256_VMC(0);
        }
        __builtin_amdgcn_s_barrier();        // buf c^1 (tile t+1) visible
        G256_SB();
    }

    if constexpr (MODE == 6) {
        bf16* C = (bf16*)Cv;
#pragma unroll
        for (int mi = 0; mi < 8; mi++) {
#pragma unroll
            for (int ni = 0; ni < 2; ni++) {
                const int row = m0 + wm * 128 + mi * 16 + lq * 4;
                const int col = n0 + wn * 32 + ni * 16 + lm;
#pragma unroll
                for (int r = 0; r < 4; r++) {
                    float v1 = acc[mi][ni][r];
                    float v3 = acc[mi][ni + 2][r];
                    C[(long long)(row + r) * ldc + col] =
                        (bf16)((v1 / (1.f + __expf(-v1))) * v3);
                }
            }
        }
    } else {
#pragma unroll
        for (int mi = 0; mi < 8; mi++) {
#pragma unroll
            for (int ni = 0; ni < NIE; ni++) {
                const int row = m0 + wm * 128 + mi * 16 + lq * 4;
                const int col = n0 + wn * bw + ni * 16 + lm;
#pragma unroll
                for (int r = 0; r < 4; r++) {
                    float v = alpha * acc[mi][ni][r];
                    long long rr = row + r;
                    if constexpr (MODE == 0) {
                        bf16* C = (bf16*)Cv;
                        C[rr * ldc + col] = (bf16)v;
                    } else if constexpr (MODE == 2) {
                        float* C = (float*)Cv;
                        C[rr * ldc + col] += v;       // exclusive tile
                    } else {   // MODE 5
                        int bb2 = (int)(rr >> 10);
                        int s = selp[rr];
                        float add = rwp[rr] * (v + res[rr * (long long)ND + col]);
                        outp[((long long)bb2 * NS + s) * ND + col] += add;  // exclusive
                    }
                }
            }
        }
    }
}

// ---------------------------------------------------------------------------
extern "C" void kernel_launch(void* const* d_in, const int* in_sizes, int n_in,
                              void* d_out, int out_size, void* d_ws, size_t ws_size,
                              hipStream_t stream) {
    const float* x  = (const float*)d_in[0];
    const float* fr = (const float*)d_in[2];
    const float* wr = (const float*)d_in[3];
    const float* g1 = (const float*)d_in[4];
    const float* wq = (const float*)d_in[5];
    const float* wk = (const float*)d_in[6];
    const float* wv = (const float*)d_in[7];
    const float* wo = (const float*)d_in[8];
    const float* g2 = (const float*)d_in[9];
    const float* w1 = (const float*)d_in[10];
    const float* w3 = (const float*)d_in[11];
    const float* w2 = (const float*)d_in[12];
    float* out = (float*)d_out;

    char* ws = (char*)d_ws;
    size_t off = 0;
    auto take = [&](size_t bytes) -> char* {
        char* p = ws + off;
        off += (bytes + 255) & ~(size_t)255;
        return p;
    };
    int*   sel    = (int*)take((size_t)NB * NT * 4);
    float* rw     = (float*)take((size_t)NB * NT * 4);
    float* logits = (float*)take((size_t)NB * NS * 4);
    float* xf     = (float*)take((size_t)NB * NT * ND * 4);
    bf16*  hbuf   = (bf16*)take((size_t)NB * NT * ND * 2);
    bf16*  wqkv_t = (bf16*)take((size_t)3 * ND * ND * 2);
    bf16*  wo_t   = (bf16*)take((size_t)ND * ND * 2);
    bf16*  Obuf   = (bf16*)take((size_t)NB * NT * ND * 2);
    char* xr = ws + off;
    // attention-phase overlay
    bf16* QKV = (bf16*)xr;                               // [4096][6144]
    bf16* Qr  = QKV + (size_t)NB * NT * 3 * ND;
    bf16* Kr  = Qr + (size_t)NB * NT * ND;
    bf16* Vt  = Kr + (size_t)NB * NT * ND;
    // FFN-phase overlay (attention data dead by then)
    bf16* w1_t  = (bf16*)xr;
    bf16* w3_t  = w1_t + (size_t)ND * NF;
    bf16* w2_t  = w3_t + (size_t)ND * NF;
    bf16* inter = w2_t + (size_t)ND * NF;

    router_k<<<NB * NS, 256, 0, stream>>>(x, wr, logits);
    topk_k<<<NB, 1024, 0, stream>>>(logits, sel, rw);
    gather_k<<<(NB * NT * ND / 4) / 256, 256, 0, stream>>>(x, sel, xf);
    rmsnorm_k<<<NB * NT, 256, 0, stream>>>(xf, g1, hbuf);

    dim3 tg(ND / 32, ND / 32);
    transpose_to_bf16<<<tg, 256, 0, stream>>>(wq, wqkv_t, ND, ND);
    transpose_to_bf16<<<tg, 256, 0, stream>>>(wk, wqkv_t + (size_t)ND * ND, ND, ND);
    transpose_to_bf16<<<tg, 256, 0, stream>>>(wv, wqkv_t + (size_t)2 * ND * ND, ND, ND);
    transpose_to_bf16<<<tg, 256, 0, stream>>>(wo, wo_t, ND, ND);

    // fused QKV: [4096 x 2048] x [6144 x 2048]^T -> [4096][6144]
    gemm256<0><<<dim3(3 * ND / 256, NB * NT / 256, 1), 512, 0, stream>>>(
        hbuf, ND, wqkv_t, ND, QKV, 3 * ND, ND, 1.0f,
        nullptr, nullptr, nullptr, nullptr, nullptr);

    rope_qk_k<<<(NB * NT * NH * 64) / 256, 256, 0, stream>>>(QKV, fr, Qr, Kr);
    vtr_k<<<dim3(NT / 64, NB * NH), 256, 0, stream>>>(QKV, Vt);

    // fused flash attention
    flash_k<<<dim3(NT / 128, NB * NH), 256, 0, stream>>>(Qr, Kr, Vt, Obuf);

    // WO: 128-N tiles, single-z, non-atomic += into xf residual
    gemm256<2><<<dim3(ND / 128, NB * NT / 256, 1), 512, 0, stream>>>(
        Obuf, ND, wo_t, ND, xf, ND, ND, 1.0f,
        nullptr, nullptr, nullptr, nullptr, nullptr);

    rmsnorm_k<<<NB * NT, 256, 0, stream>>>(xf, g2, hbuf);

    transpose_to_bf16<<<dim3(NF / 32, ND / 32), 256, 0, stream>>>(w1, w1_t, ND, NF);
    transpose_to_bf16<<<dim3(NF / 32, ND / 32), 256, 0, stream>>>(w3, w3_t, ND, NF);
    transpose_to_bf16<<<dim3(ND / 32, NF / 32), 256, 0, stream>>>(w2, w2_t, NF, ND);

    // fused FFN up: inter = silu(h.w1) * (h.w3)
    gemm256<6><<<dim3(NF / 128, NB * NT / 256, 1), 512, 0, stream>>>(
        hbuf, ND, w1_t, ND, inter, NF, ND, 1.0f,
        w3_t, nullptr, nullptr, nullptr, nullptr);

    copy_k<<<8192, 256, 0, stream>>>((const float4*)x, (float4*)out,
                                     (long long)NB * NS * ND / 4);
    // w2 + scatter-add: 128-N tiles, single-z, non-atomic (tiles exclusive)
    gemm256<5><<<dim3(ND / 128, NB * NT / 256, 1), 512, 0, stream>>>(
        inter, NF, w2_t, NF, nullptr, ND, NF, 1.0f,
        nullptr, xf, sel, rw, out);
}